// Round 1
// baseline (571.157 us; speedup 1.0000x reference)
//
#include <hip/hip_runtime.h>

typedef unsigned short u16;
typedef unsigned int u32;

#define D_MODEL 1024
#define N_HEADS 16
#define D_HEAD 64
#define WIN 256
#define SEQ 2048
#define BATCH 2
#define NROWS (BATCH*SEQ)          // 4096 token rows

typedef short frag_ab __attribute__((ext_vector_type(8)));   // 8 bf16 (4 VGPRs)
typedef float frag_cd __attribute__((ext_vector_type(4)));   // 4 fp32

__device__ __forceinline__ u16 f2bf(float f) {
    union { float f; u32 u; } x; x.f = f;
    u32 r = x.u + 0x7fffu + ((x.u >> 16) & 1u);   // RNE
    return (u16)(r >> 16);
}
__device__ __forceinline__ float bf2f(u16 v) {
    union { u32 u; float f; } x; x.u = ((u32)v) << 16; return x.f;
}
__device__ __forceinline__ float bflo(u32 u) { union { u32 u; float f; } x; x.u = u << 16; return x.f; }
__device__ __forceinline__ float bfhi(u32 u) { union { u32 u; float f; } x; x.u = u & 0xffff0000u; return x.f; }

__device__ __forceinline__ void load_lds16(const void* g, void* l) {
    __builtin_amdgcn_global_load_lds(
        (const __attribute__((address_space(1))) void*)g,
        (__attribute__((address_space(3))) void*)l, 16, 0, 0);
}

// ---------------- cast x -> bf16 ----------------
__global__ void cast_kernel(const float4* __restrict__ in, ushort4* __restrict__ out, int n4) {
    int idx = blockIdx.x * blockDim.x + threadIdx.x;
    if (idx < n4) {
        float4 v = in[idx];
        ushort4 o;
        o.x = f2bf(v.x); o.y = f2bf(v.y); o.z = f2bf(v.z); o.w = f2bf(v.w);
        out[idx] = o;
    }
}

// ---------------- transpose-cast W[K,N] f32 -> WT[N,K] bf16 ----------------
__global__ void transpose_cast(const float* __restrict__ W, u16* __restrict__ WT, int K, int N) {
    __shared__ float tile[32][33];
    int n0 = blockIdx.x * 32, k0 = blockIdx.y * 32;
    int x = threadIdx.x, y = threadIdx.y;   // 32 x 8
#pragma unroll
    for (int r = 0; r < 4; r++)
        tile[y + 8 * r][x] = W[(size_t)(k0 + y + 8 * r) * N + n0 + x];
    __syncthreads();
#pragma unroll
    for (int r = 0; r < 4; r++)
        WT[(size_t)(n0 + y + 8 * r) * K + k0 + x] = f2bf(tile[x][y + 8 * r]);
}

// ---------------- bf16 GEMM: C[M,N] = A[M,K] * BT[N,K]^T ----------------
// m97 structure: 128x128 tile, BK=32, 256 threads (4 waves, 2x2), 4x4 16x16x32 MFMAs/wave
template <bool BF16_OUT>
__global__ __launch_bounds__(256) void gemm128(const u16* __restrict__ A,
                                               const u16* __restrict__ BT,
                                               void* __restrict__ C,
                                               int M, int N, int K) {
    __shared__ u16 As[128 * 32];
    __shared__ u16 Bs[128 * 32];
    const int tid = threadIdx.x;
    const int m0 = blockIdx.y * 128, n0 = blockIdx.x * 128;
    const int wave = tid >> 6, lane = tid & 63;
    const int wm = (wave >> 1) * 64, wn = (wave & 1) * 64;
    const int lrow = lane & 15, quad = lane >> 4;

    frag_cd acc[4][4] = {};

    const int c0 = tid, c1 = tid + 256;
    const int r0 = c0 >> 2, w0 = c0 & 3;
    const int r1 = c1 >> 2, w1 = c1 & 3;
    const u16* a0 = A + (size_t)(m0 + r0) * K + w0 * 8;
    const u16* a1 = A + (size_t)(m0 + r1) * K + w1 * 8;
    const u16* b0 = BT + (size_t)(n0 + r0) * K + w0 * 8;
    const u16* b1 = BT + (size_t)(n0 + r1) * K + w1 * 8;

    for (int k0 = 0; k0 < K; k0 += 32) {
        __syncthreads();                       // previous compute done before overwrite
        load_lds16(a0 + k0, &As[c0 * 8]);
        load_lds16(a1 + k0, &As[c1 * 8]);
        load_lds16(b0 + k0, &Bs[c0 * 8]);
        load_lds16(b1 + k0, &Bs[c1 * 8]);
        __syncthreads();                       // drains vmcnt -> tiles visible

        frag_ab af[4], bf[4];
#pragma unroll
        for (int t = 0; t < 4; t++) {
            af[t] = *(const frag_ab*)&As[(wm + t * 16 + lrow) * 32 + quad * 8];
            bf[t] = *(const frag_ab*)&Bs[(wn + t * 16 + lrow) * 32 + quad * 8];
        }
#pragma unroll
        for (int mt = 0; mt < 4; mt++)
#pragma unroll
            for (int nt = 0; nt < 4; nt++)
                acc[mt][nt] = __builtin_amdgcn_mfma_f32_16x16x32_bf16(af[mt], bf[nt], acc[mt][nt], 0, 0, 0);
    }

    // epilogue: C/D layout col=lane&15, row=quad*4+reg  [m89-verified]
#pragma unroll
    for (int mt = 0; mt < 4; mt++) {
#pragma unroll
        for (int nt = 0; nt < 4; nt++) {
            int col = n0 + wn + nt * 16 + lrow;
#pragma unroll
            for (int r = 0; r < 4; r++) {
                int row = m0 + wm + mt * 16 + quad * 4 + r;
                float v = acc[mt][nt][r];
                if (BF16_OUT) ((u16*)C)[(size_t)row * N + col] = f2bf(v);
                else          ((float*)C)[(size_t)row * N + col] = v;
            }
        }
    }
}

// ---------------- sliding-window attention: one wave per (b,h,i) row ----------------
// qkv: [B*S, 3072] bf16  (q at col h*64, k at 1024+h*64, v at 2048+h*64)
// out: [B*S, 1024] bf16  (col h*64+d)
__global__ __launch_bounds__(256) void attn_kernel(const u16* __restrict__ qkv, u16* __restrict__ out) {
    __shared__ float qs[4][64];
    __shared__ float ps[4][256];
    const int wave = threadIdx.x >> 6, lane = threadIdx.x & 63;
    const int r = blockIdx.x * 4 + wave;           // [0, B*H*S)
    const int b = r >> 15;                          // / (H*S)
    const int h = (r >> 11) & 15;
    const int i = r & 2047;

    const size_t rowq = (size_t)(b * SEQ + i) * 3072 + h * 64;
    qs[wave][lane] = bf2f(qkv[rowq + lane]);
    __syncthreads();

    const int jstart = (i >= WIN - 1) ? (i - (WIN - 1)) : 0;
    const int cnt = i - jstart + 1;

    float sc[4];
#pragma unroll
    for (int p = 0; p < 4; p++) {
        int j = jstart + p * 64 + lane;
        if (j <= i) {
            const uint4* kp = (const uint4*)(qkv + (size_t)(b * SEQ + j) * 3072 + 1024 + h * 64);
            float acc = 0.f;
#pragma unroll
            for (int c = 0; c < 8; c++) {
                uint4 kk = kp[c];
                const float* q8 = &qs[wave][c * 8];
                acc += q8[0] * bflo(kk.x) + q8[1] * bfhi(kk.x);
                acc += q8[2] * bflo(kk.y) + q8[3] * bfhi(kk.y);
                acc += q8[4] * bflo(kk.z) + q8[5] * bfhi(kk.z);
                acc += q8[6] * bflo(kk.w) + q8[7] * bfhi(kk.w);
            }
            sc[p] = acc * 0.125f;
        } else {
            sc[p] = -1e30f;
        }
    }

    float m = fmaxf(fmaxf(sc[0], sc[1]), fmaxf(sc[2], sc[3]));
#pragma unroll
    for (int off = 32; off > 0; off >>= 1) m = fmaxf(m, __shfl_xor(m, off));

    float sum = 0.f;
#pragma unroll
    for (int p = 0; p < 4; p++) {
        float e = (sc[p] > -1e29f) ? __expf(sc[p] - m) : 0.f;
        ps[wave][p * 64 + lane] = e;
        sum += e;
    }
#pragma unroll
    for (int off = 32; off > 0; off >>= 1) sum += __shfl_xor(sum, off);
    const float inv = 1.f / sum;
    __syncthreads();

    // PV: lane = d
    float acc = 0.f;
    const u16* vbase = qkv + (size_t)(b * SEQ + jstart) * 3072 + 2048 + h * 64 + lane;
    for (int j = 0; j < cnt; j++)
        acc += ps[wave][j] * bf2f(vbase[(size_t)j * 3072]);

    out[(size_t)(b * SEQ + i) * 1024 + h * 64 + lane] = f2bf(acc * inv);
}

extern "C" void kernel_launch(void* const* d_in, const int* in_sizes, int n_in,
                              void* d_out, int out_size, void* d_ws, size_t ws_size,
                              hipStream_t stream) {
    const float* x     = (const float*)d_in[0];   // [2,2048,1024]
    const float* W_qkv = (const float*)d_in[1];   // [1024,3072]
    const float* W_out = (const float*)d_in[2];   // [1024,1024]
    float* out = (float*)d_out;                   // [2,2048,1024]

    char* ws = (char*)d_ws;
    u16* xb    = (u16*)(ws);                       //  8,388,608 B : x bf16 [4096,1024]
    u16* wqkvT = (u16*)(ws + 8388608);             //  6,291,456 B : W_qkv^T bf16 [3072,1024]
    u16* woutT = (u16*)(ws + 14680064);            //  2,097,152 B : W_out^T bf16 [1024,1024]
    u16* qkvb  = (u16*)(ws + 16777216);            // 25,165,824 B : qkv bf16 [4096,3072]
    u16* attnb = (u16*)(ws + 41943040);            //  8,388,608 B : attn out bf16 [4096,1024]

    // 1. casts / transposes
    {
        int n4 = NROWS * D_MODEL / 4;
        cast_kernel<<<(n4 + 255) / 256, 256, 0, stream>>>((const float4*)x, (ushort4*)xb, n4);
        transpose_cast<<<dim3(3 * D_MODEL / 32, D_MODEL / 32), dim3(32, 8), 0, stream>>>(W_qkv, wqkvT, D_MODEL, 3 * D_MODEL);
        transpose_cast<<<dim3(D_MODEL / 32, D_MODEL / 32), dim3(32, 8), 0, stream>>>(W_out, woutT, D_MODEL, D_MODEL);
    }
    // 2. qkv = x @ W_qkv   [4096,3072] bf16
    gemm128<true><<<dim3(3 * D_MODEL / 128, NROWS / 128), 256, 0, stream>>>(xb, wqkvT, qkvb, NROWS, 3 * D_MODEL, D_MODEL);
    // 3. attention
    attn_kernel<<<BATCH * N_HEADS * SEQ / 4, 256, 0, stream>>>(qkvb, attnb);
    // 4. out = attn @ W_out  -> fp32
    gemm128<false><<<dim3(D_MODEL / 128, NROWS / 128), 256, 0, stream>>>(attnb, woutT, out, NROWS, D_MODEL, D_MODEL);
}

// Round 2
// 174.282 us; speedup vs baseline: 3.2772x; 3.2772x over previous
//
#include <hip/hip_runtime.h>

typedef unsigned short u16;
typedef unsigned int u32;

#define D_MODEL 1024
#define N_HEADS 16
#define D_HEAD 64
#define WIN 256
#define SEQ 2048
#define BATCH 2
#define NROWS (BATCH*SEQ)          // 4096 token rows

typedef short frag_ab __attribute__((ext_vector_type(8)));   // 8 bf16 (4 VGPRs)
typedef float frag_cd __attribute__((ext_vector_type(4)));   // 4 fp32
typedef u16 u16x8 __attribute__((ext_vector_type(8)));

__device__ __forceinline__ u16 f2bf(float f) {
    union { float f; u32 u; } x; x.f = f;
    u32 r = x.u + 0x7fffu + ((x.u >> 16) & 1u);   // RNE
    return (u16)(r >> 16);
}
__device__ __forceinline__ float bf2f(u16 v) {
    union { u32 u; float f; } x; x.u = ((u32)v) << 16; return x.f;
}

__device__ __forceinline__ void load_lds16(const void* g, void* l) {
    __builtin_amdgcn_global_load_lds(
        (const __attribute__((address_space(1))) void*)g,
        (__attribute__((address_space(3))) void*)l, 16, 0, 0);
}

// ---------------- cast x -> bf16 ----------------
__global__ void cast_kernel(const float4* __restrict__ in, ushort4* __restrict__ out, int n4) {
    int idx = blockIdx.x * blockDim.x + threadIdx.x;
    if (idx < n4) {
        float4 v = in[idx];
        ushort4 o;
        o.x = f2bf(v.x); o.y = f2bf(v.y); o.z = f2bf(v.z); o.w = f2bf(v.w);
        out[idx] = o;
    }
}

// ---------------- transpose-cast W[K,N] f32 -> WT[N,K] bf16 (rows < scale_rows get *scale) ----
__global__ void transpose_cast(const float* __restrict__ W, u16* __restrict__ WT, int K, int N,
                               int scale_rows, float scale) {
    __shared__ float tile[32][33];
    int n0 = blockIdx.x * 32, k0 = blockIdx.y * 32;
    int x = threadIdx.x, y = threadIdx.y;   // 32 x 8
#pragma unroll
    for (int r = 0; r < 4; r++)
        tile[y + 8 * r][x] = W[(size_t)(k0 + y + 8 * r) * N + n0 + x];
    __syncthreads();
#pragma unroll
    for (int r = 0; r < 4; r++) {
        int nrow = n0 + y + 8 * r;
        float v = tile[x][y + 8 * r];
        if (nrow < scale_rows) v *= scale;
        WT[(size_t)nrow * K + k0 + x] = f2bf(v);
    }
}

// ---------------- bf16 GEMM: C[M,N] = A[M,K] * BT[N,K]^T ----------------
template <bool BF16_OUT>
__global__ __launch_bounds__(256) void gemm128(const u16* __restrict__ A,
                                               const u16* __restrict__ BT,
                                               void* __restrict__ C,
                                               int M, int N, int K) {
    __shared__ u16 As[128 * 32];
    __shared__ u16 Bs[128 * 32];
    const int tid = threadIdx.x;
    const int m0 = blockIdx.y * 128, n0 = blockIdx.x * 128;
    const int wave = tid >> 6, lane = tid & 63;
    const int wm = (wave >> 1) * 64, wn = (wave & 1) * 64;
    const int lrow = lane & 15, quad = lane >> 4;

    frag_cd acc[4][4] = {};

    const int c0 = tid, c1 = tid + 256;
    const int r0 = c0 >> 2, w0 = c0 & 3;
    const int r1 = c1 >> 2, w1 = c1 & 3;
    const u16* a0 = A + (size_t)(m0 + r0) * K + w0 * 8;
    const u16* a1 = A + (size_t)(m0 + r1) * K + w1 * 8;
    const u16* b0 = BT + (size_t)(n0 + r0) * K + w0 * 8;
    const u16* b1 = BT + (size_t)(n0 + r1) * K + w1 * 8;

    for (int k0 = 0; k0 < K; k0 += 32) {
        __syncthreads();
        load_lds16(a0 + k0, &As[c0 * 8]);
        load_lds16(a1 + k0, &As[c1 * 8]);
        load_lds16(b0 + k0, &Bs[c0 * 8]);
        load_lds16(b1 + k0, &Bs[c1 * 8]);
        __syncthreads();

        frag_ab af[4], bf[4];
#pragma unroll
        for (int t = 0; t < 4; t++) {
            af[t] = *(const frag_ab*)&As[(wm + t * 16 + lrow) * 32 + quad * 8];
            bf[t] = *(const frag_ab*)&Bs[(wn + t * 16 + lrow) * 32 + quad * 8];
        }
#pragma unroll
        for (int mt = 0; mt < 4; mt++)
#pragma unroll
            for (int nt = 0; nt < 4; nt++)
                acc[mt][nt] = __builtin_amdgcn_mfma_f32_16x16x32_bf16(af[mt], bf[nt], acc[mt][nt], 0, 0, 0);
    }

#pragma unroll
    for (int mt = 0; mt < 4; mt++) {
#pragma unroll
        for (int nt = 0; nt < 4; nt++) {
            int col = n0 + wn + nt * 16 + lrow;
#pragma unroll
            for (int r = 0; r < 4; r++) {
                int row = m0 + wm + mt * 16 + quad * 4 + r;
                float v = acc[mt][nt][r];
                if (BF16_OUT) ((u16*)C)[(size_t)row * N + col] = f2bf(v);
                else          ((float*)C)[(size_t)row * N + col] = v;
            }
        }
    }
}

// ---------------- MFMA flash attention (sliding window) ----------------
// qkv [B*S, 3072] bf16 (q cols scaled by SCALE*log2e), out [B*S, 1024] bf16.
// One workgroup = 64 q-rows of one (b,h); 4 waves x 16 rows. K-tiles of 64
// keys iterated in DESCENDING j (first tile contains each row's diagonal ->
// running max always valid before any fully-masked row appears).
__global__ __launch_bounds__(256) void attn_kernel(const u16* __restrict__ qkv, u16* __restrict__ out) {
    __shared__ u16 Ks[64 * 64];          // XOR-chunk-swizzled: chunk c of row r stored at c^(r&7)
    __shared__ u16 Vt[64 * 72];          // Vt[d][j], row pad +8
    __shared__ u16 ps[4][16 * 72];       // per-wave P tile, row pad +8

    const int tid = threadIdx.x;
    const int wave = tid >> 6, lane = tid & 63;
    const int quad = lane >> 4, c16 = lane & 15;

    const int qc = blockIdx.x & 31;
    const int h  = (blockIdx.x >> 5) & 15;
    const int b  = blockIdx.x >> 9;
    const int q0 = qc * 64;
    const int qw0 = q0 + wave * 16;

    // Q frags (A-layout: m=c16, k=quad*8+j), d=64 -> 2 frags
    frag_ab qf[2];
    {
        const u16* qrow = qkv + (size_t)(b * SEQ + qw0 + c16) * 3072 + h * 64;
        qf[0] = *(const frag_ab*)(qrow + quad * 8);
        qf[1] = *(const frag_ab*)(qrow + 32 + quad * 8);
    }

    float m_r[4], l_r[4];
    frag_cd acc[4] = {};                 // acc[dblk]: O accumulator, C-layout
#pragma unroll
    for (int r = 0; r < 4; r++) { m_r[r] = -1e30f; l_r[r] = 0.f; }

    const int ntiles = qc < 4 ? qc + 1 : 5;

    // K staging: row_local = wave*16 + it*8 + (lane>>3); stored chunk pos = lane&7,
    // fetched original chunk = (lane&7) ^ (lane>>3)   [since (row_local&7)==(lane>>3)]
    const int krow = wave * 16 + (lane >> 3);
    const int kchunk = (lane & 7) ^ (lane >> 3);
    const int vj = tid & 63, vdblk = tid >> 6;

    for (int t = 0; t < ntiles; t++) {
        const int j0 = q0 - 64 * t;
        __syncthreads();                 // everyone done with previous Ks/Vt
        {
            const u16* g = qkv + (size_t)(b * SEQ + j0 + krow) * 3072 + 1024 + h * 64 + kchunk * 8;
            load_lds16(g,            &Ks[krow * 64 + (lane & 7) * 8]);
            load_lds16(g + 8 * 3072, &Ks[(krow + 8) * 64 + (lane & 7) * 8]);
        }
        {
            const u16* g = qkv + (size_t)(b * SEQ + j0 + vj) * 3072 + 2048 + h * 64 + vdblk * 16;
            u16x8 v0 = *(const u16x8*)g;
            u16x8 v1 = *(const u16x8*)(g + 8);
#pragma unroll
            for (int dd = 0; dd < 8; dd++) Vt[(vdblk * 16 + dd) * 72 + vj] = v0[dd];
#pragma unroll
            for (int dd = 0; dd < 8; dd++) Vt[(vdblk * 16 + 8 + dd) * 72 + vj] = v1[dd];
        }
        __syncthreads();                 // Ks/Vt visible (vmcnt+lgkm drained by barrier)

        // QK^T: scores s[kb] (16q x 16k each), kb over 64 keys
        frag_cd s[4] = {};
#pragma unroll
        for (int kb = 0; kb < 4; kb++) {
            frag_ab kf0 = *(const frag_ab*)&Ks[(kb * 16 + c16) * 64 + ((quad    ) ^ (c16 & 7)) * 8];
            frag_ab kf1 = *(const frag_ab*)&Ks[(kb * 16 + c16) * 64 + ((4 + quad) ^ (c16 & 7)) * 8];
            s[kb] = __builtin_amdgcn_mfma_f32_16x16x32_bf16(qf[0], kf0, s[kb], 0, 0, 0);
            s[kb] = __builtin_amdgcn_mfma_f32_16x16x32_bf16(qf[1], kf1, s[kb], 0, 0, 0);
        }

        // mask (scores already in log2 domain via scaled q)
        float mt[4];
#pragma unroll
        for (int reg = 0; reg < 4; reg++) {
            const int i = qw0 + quad * 4 + reg;
#pragma unroll
            for (int kb = 0; kb < 4; kb++) {
                const int j = j0 + kb * 16 + c16;
                if (j > i || j + WIN <= i) s[kb][reg] = -1e30f;
            }
            mt[reg] = fmaxf(fmaxf(s[0][reg], s[1][reg]), fmaxf(s[2][reg], s[3][reg]));
        }
#pragma unroll
        for (int off = 1; off < 16; off <<= 1)
#pragma unroll
            for (int reg = 0; reg < 4; reg++) mt[reg] = fmaxf(mt[reg], __shfl_xor(mt[reg], off));

        float alpha[4], rs[4];
#pragma unroll
        for (int reg = 0; reg < 4; reg++) {
            float mn = fmaxf(m_r[reg], mt[reg]);
            alpha[reg] = __builtin_amdgcn_exp2f(m_r[reg] - mn);
            m_r[reg] = mn;
            rs[reg] = 0.f;
        }
#pragma unroll
        for (int kb = 0; kb < 4; kb++)
#pragma unroll
            for (int reg = 0; reg < 4; reg++) {
                float p = __builtin_amdgcn_exp2f(s[kb][reg] - m_r[reg]);
                u16 pb = f2bf(p);
                ps[wave][(quad * 4 + reg) * 72 + kb * 16 + c16] = pb;
                rs[reg] += bf2f(pb);
            }
#pragma unroll
        for (int off = 1; off < 16; off <<= 1)
#pragma unroll
            for (int reg = 0; reg < 4; reg++) rs[reg] += __shfl_xor(rs[reg], off);
#pragma unroll
        for (int reg = 0; reg < 4; reg++) l_r[reg] = l_r[reg] * alpha[reg] + rs[reg];
#pragma unroll
        for (int dblk = 0; dblk < 4; dblk++)
#pragma unroll
            for (int reg = 0; reg < 4; reg++) acc[dblk][reg] *= alpha[reg];

        // PV: A = P (wave-local ps, same-wave ds ordering), B = Vt
#pragma unroll
        for (int js = 0; js < 2; js++) {
            frag_ab pf = *(const frag_ab*)&ps[wave][c16 * 72 + js * 32 + quad * 8];
#pragma unroll
            for (int dblk = 0; dblk < 4; dblk++) {
                frag_ab vf = *(const frag_ab*)&Vt[(dblk * 16 + c16) * 72 + js * 32 + quad * 8];
                acc[dblk] = __builtin_amdgcn_mfma_f32_16x16x32_bf16(pf, vf, acc[dblk], 0, 0, 0);
            }
        }
    }

    float inv[4];
#pragma unroll
    for (int reg = 0; reg < 4; reg++) inv[reg] = 1.f / l_r[reg];
#pragma unroll
    for (int dblk = 0; dblk < 4; dblk++)
#pragma unroll
        for (int reg = 0; reg < 4; reg++)
            out[(size_t)(b * SEQ + qw0 + quad * 4 + reg) * 1024 + h * 64 + dblk * 16 + c16] =
                f2bf(acc[dblk][reg] * inv[reg]);
}

extern "C" void kernel_launch(void* const* d_in, const int* in_sizes, int n_in,
                              void* d_out, int out_size, void* d_ws, size_t ws_size,
                              hipStream_t stream) {
    const float* x     = (const float*)d_in[0];   // [2,2048,1024]
    const float* W_qkv = (const float*)d_in[1];   // [1024,3072]
    const float* W_out = (const float*)d_in[2];   // [1024,1024]
    float* out = (float*)d_out;                   // [2,2048,1024]

    char* ws = (char*)d_ws;
    u16* xb    = (u16*)(ws);                       //  8 MB : x bf16 [4096,1024]
    u16* wqkvT = (u16*)(ws + 8388608);             //  6 MB : W_qkv^T bf16 [3072,1024] (q rows pre-scaled)
    u16* woutT = (u16*)(ws + 14680064);            //  2 MB : W_out^T bf16 [1024,1024]
    u16* qkvb  = (u16*)(ws + 16777216);            // 24 MB : qkv bf16 [4096,3072]
    u16* attnb = (u16*)(ws + 41943040);            //  8 MB : attn out bf16 [4096,1024]

    const float QSCALE = 0.125f * 1.4426950408889634f;  // 1/sqrt(64) * log2(e)

    {
        int n4 = NROWS * D_MODEL / 4;
        cast_kernel<<<(n4 + 255) / 256, 256, 0, stream>>>((const float4*)x, (ushort4*)xb, n4);
        transpose_cast<<<dim3(3 * D_MODEL / 32, D_MODEL / 32), dim3(32, 8), 0, stream>>>(
            W_qkv, wqkvT, D_MODEL, 3 * D_MODEL, D_MODEL, QSCALE);
        transpose_cast<<<dim3(D_MODEL / 32, D_MODEL / 32), dim3(32, 8), 0, stream>>>(
            W_out, woutT, D_MODEL, D_MODEL, 0, 1.0f);
    }
    gemm128<true><<<dim3(3 * D_MODEL / 128, NROWS / 128), 256, 0, stream>>>(xb, wqkvT, qkvb, NROWS, 3 * D_MODEL, D_MODEL);
    attn_kernel<<<BATCH * N_HEADS * (SEQ / 64), 256, 0, stream>>>(qkvb, attnb);
    gemm128<false><<<dim3(D_MODEL / 128, NROWS / 128), 256, 0, stream>>>(attnb, woutT, out, NROWS, D_MODEL, D_MODEL);
}

// Round 3
// 158.208 us; speedup vs baseline: 3.6102x; 1.1016x over previous
//
#include <hip/hip_runtime.h>

typedef unsigned short u16;
typedef unsigned int u32;

#define D_MODEL 1024
#define N_HEADS 16
#define D_HEAD 64
#define WIN 256
#define SEQ 2048
#define BATCH 2
#define NROWS (BATCH*SEQ)          // 4096 token rows

typedef short frag_ab __attribute__((ext_vector_type(8)));   // 8 bf16 (4 VGPRs)
typedef float frag_cd __attribute__((ext_vector_type(4)));   // 4 fp32
typedef u16 u16x8 __attribute__((ext_vector_type(8)));

__device__ __forceinline__ u16 f2bf(float f) {
    union { float f; u32 u; } x; x.f = f;
    u32 r = x.u + 0x7fffu + ((x.u >> 16) & 1u);   // RNE
    return (u16)(r >> 16);
}
__device__ __forceinline__ float bf2f(u16 v) {
    union { u32 u; float f; } x; x.u = ((u32)v) << 16; return x.f;
}

__device__ __forceinline__ void load_lds16(const void* g, void* l) {
    __builtin_amdgcn_global_load_lds(
        (const __attribute__((address_space(1))) void*)g,
        (__attribute__((address_space(3))) void*)l, 16, 0, 0);
}

// ---------------- cast x -> bf16 ----------------
__global__ void cast_kernel(const float4* __restrict__ in, ushort4* __restrict__ out, int n4) {
    int idx = blockIdx.x * blockDim.x + threadIdx.x;
    if (idx < n4) {
        float4 v = in[idx];
        ushort4 o;
        o.x = f2bf(v.x); o.y = f2bf(v.y); o.z = f2bf(v.z); o.w = f2bf(v.w);
        out[idx] = o;
    }
}

// ---------------- transpose-cast W[K,N] f32 -> WT[N,K] bf16 (rows < scale_rows get *scale) ----
__global__ void transpose_cast(const float* __restrict__ W, u16* __restrict__ WT, int K, int N,
                               int scale_rows, float scale) {
    __shared__ float tile[32][33];
    int n0 = blockIdx.x * 32, k0 = blockIdx.y * 32;
    int x = threadIdx.x, y = threadIdx.y;   // 32 x 8
#pragma unroll
    for (int r = 0; r < 4; r++)
        tile[y + 8 * r][x] = W[(size_t)(k0 + y + 8 * r) * N + n0 + x];
    __syncthreads();
#pragma unroll
    for (int r = 0; r < 4; r++) {
        int nrow = n0 + y + 8 * r;
        float v = tile[x][y + 8 * r];
        if (nrow < scale_rows) v *= scale;
        WT[(size_t)nrow * K + k0 + x] = f2bf(v);
    }
}

// ---------------- bf16 GEMM: C[M,N(tile 128)] = A[M,K] * BT[N,K]^T, BK=64 ----------------
// LDS row = 64 u16 = 8 chunks of 16B. Global chunk w stored at position w^(row&7)
// (global-side swizzle; LDS dest must stay base+lane*16 for global_load_lds).
// Frag read of chunk c of row R is at position c^(R&7); R&7 == lrow&7.
template <bool BF16_OUT, int BM>
__global__ __launch_bounds__(256) void gemm_bk64(const u16* __restrict__ A,
                                                 const u16* __restrict__ BT,
                                                 void* __restrict__ C,
                                                 int M, int N, int K) {
    constexpr int MWAVE = BM / 2;      // rows per wave-pair group
    constexpr int MT = BM / 32;        // m-tiles per wave (4 or 2)
    __shared__ u16 As[BM * 64];
    __shared__ u16 Bs[128 * 64];
    const int tid = threadIdx.x;
    const int m0 = blockIdx.y * BM, n0 = blockIdx.x * 128;
    const int wave = tid >> 6, lane = tid & 63;
    const int wm = (wave >> 1) * MWAVE, wn = (wave & 1) * 64;
    const int lrow = lane & 15, quad = lane >> 4;

    frag_cd acc[MT][4] = {};

    const int r0 = tid >> 3;                   // 0..31
    const int w  = (tid & 7) ^ (r0 & 7);       // swizzled source chunk (same for all u: +32u keeps low 3 bits)
    const u16* aP = A  + (size_t)(m0 + r0) * K + w * 8;
    const u16* bP = BT + (size_t)(n0 + r0) * K + w * 8;

    for (int k0 = 0; k0 < K; k0 += 64) {
        __syncthreads();
#pragma unroll
        for (int u = 0; u < BM / 32; u++)
            load_lds16(aP + (size_t)(32 * u) * K + k0, &As[(tid + 256 * u) * 8]);
#pragma unroll
        for (int u = 0; u < 4; u++)
            load_lds16(bP + (size_t)(32 * u) * K + k0, &Bs[(tid + 256 * u) * 8]);
        __syncthreads();

#pragma unroll
        for (int ko = 0; ko < 2; ko++) {
            const int csel = ((ko * 4 + quad) ^ (lrow & 7)) * 8;
            frag_ab af[MT], bf[4];
#pragma unroll
            for (int t = 0; t < MT; t++)
                af[t] = *(const frag_ab*)&As[(wm + t * 16 + lrow) * 64 + csel];
#pragma unroll
            for (int t = 0; t < 4; t++)
                bf[t] = *(const frag_ab*)&Bs[(wn + t * 16 + lrow) * 64 + csel];
#pragma unroll
            for (int mt = 0; mt < MT; mt++)
#pragma unroll
                for (int nt = 0; nt < 4; nt++)
                    acc[mt][nt] = __builtin_amdgcn_mfma_f32_16x16x32_bf16(af[mt], bf[nt], acc[mt][nt], 0, 0, 0);
        }
    }

    // epilogue: C/D layout col=lane&15, row=quad*4+reg  [m89-verified]
#pragma unroll
    for (int mt = 0; mt < MT; mt++) {
#pragma unroll
        for (int nt = 0; nt < 4; nt++) {
            int col = n0 + wn + nt * 16 + lrow;
#pragma unroll
            for (int r = 0; r < 4; r++) {
                int row = m0 + wm + mt * 16 + quad * 4 + r;
                float v = acc[mt][nt][r];
                if (BF16_OUT) ((u16*)C)[(size_t)row * N + col] = f2bf(v);
                else          ((float*)C)[(size_t)row * N + col] = v;
            }
        }
    }
}

// ---------------- MFMA flash attention (sliding window) ----------------
// qkv [B*S, 3072] bf16 (q cols scaled by SCALE*log2e), out [B*S, 1024] bf16.
// One workgroup = 64 q-rows of one (b,h); 4 waves x 16 rows. K-tiles of 64
// keys iterated in DESCENDING j (first tile contains each row's diagonal ->
// running max always valid before any fully-masked row appears).
__global__ __launch_bounds__(256) void attn_kernel(const u16* __restrict__ qkv, u16* __restrict__ out) {
    __shared__ u16 Ks[64 * 64];          // XOR-chunk-swizzled: chunk c of row r stored at c^(r&7)
    __shared__ u16 Vt[64 * 72];          // Vt[d][j], row pad +8
    __shared__ u16 ps[4][16 * 72];       // per-wave P tile, row pad +8

    const int tid = threadIdx.x;
    const int wave = tid >> 6, lane = tid & 63;
    const int quad = lane >> 4, c16 = lane & 15;

    const int qc = blockIdx.x & 31;
    const int h  = (blockIdx.x >> 5) & 15;
    const int b  = blockIdx.x >> 9;
    const int q0 = qc * 64;
    const int qw0 = q0 + wave * 16;

    // Q frags (A-layout: m=c16, k=quad*8+j), d=64 -> 2 frags
    frag_ab qf[2];
    {
        const u16* qrow = qkv + (size_t)(b * SEQ + qw0 + c16) * 3072 + h * 64;
        qf[0] = *(const frag_ab*)(qrow + quad * 8);
        qf[1] = *(const frag_ab*)(qrow + 32 + quad * 8);
    }

    float m_r[4], l_r[4];
    frag_cd acc[4] = {};                 // acc[dblk]: O accumulator, C-layout
#pragma unroll
    for (int r = 0; r < 4; r++) { m_r[r] = -1e30f; l_r[r] = 0.f; }

    const int ntiles = qc < 4 ? qc + 1 : 5;

    // K staging: row_local = wave*16 + (lane>>3) (+8); stored chunk pos = lane&7,
    // fetched original chunk = (lane&7) ^ (lane>>3)
    const int krow = wave * 16 + (lane >> 3);
    const int kchunk = (lane & 7) ^ (lane >> 3);
    // V staging: packed b32 writes (2 j-columns per word), conflict-free
    const int vj2 = (tid & 31) * 2, vd8 = tid >> 5;   // vd8 in 0..7 (8 d-values each)

    for (int t = 0; t < ntiles; t++) {
        const int j0 = q0 - 64 * t;
        __syncthreads();                 // everyone done with previous Ks/Vt
        {
            const u16* g = qkv + (size_t)(b * SEQ + j0 + krow) * 3072 + 1024 + h * 64 + kchunk * 8;
            load_lds16(g,            &Ks[krow * 64 + (lane & 7) * 8]);
            load_lds16(g + 8 * 3072, &Ks[(krow + 8) * 64 + (lane & 7) * 8]);
        }
        {
            const u16* g = qkv + (size_t)(b * SEQ + j0 + vj2) * 3072 + 2048 + h * 64 + vd8 * 8;
            u16x8 va = *(const u16x8*)g;
            u16x8 vb = *(const u16x8*)(g + 3072);
#pragma unroll
            for (int dd = 0; dd < 8; dd++)
                *(u32*)&Vt[(vd8 * 8 + dd) * 72 + vj2] = (u32)va[dd] | ((u32)vb[dd] << 16);
        }
        __syncthreads();                 // Ks/Vt visible (vmcnt+lgkm drained by barrier)

        // QK^T: scores s[kb] (16q x 16k each), kb over 64 keys
        frag_cd s[4] = {};
#pragma unroll
        for (int kb = 0; kb < 4; kb++) {
            frag_ab kf0 = *(const frag_ab*)&Ks[(kb * 16 + c16) * 64 + ((quad    ) ^ (c16 & 7)) * 8];
            frag_ab kf1 = *(const frag_ab*)&Ks[(kb * 16 + c16) * 64 + ((4 + quad) ^ (c16 & 7)) * 8];
            s[kb] = __builtin_amdgcn_mfma_f32_16x16x32_bf16(qf[0], kf0, s[kb], 0, 0, 0);
            s[kb] = __builtin_amdgcn_mfma_f32_16x16x32_bf16(qf[1], kf1, s[kb], 0, 0, 0);
        }

        // mask (scores already in log2 domain via scaled q)
        float mt_[4];
#pragma unroll
        for (int reg = 0; reg < 4; reg++) {
            const int i = qw0 + quad * 4 + reg;
#pragma unroll
            for (int kb = 0; kb < 4; kb++) {
                const int j = j0 + kb * 16 + c16;
                if (j > i || j + WIN <= i) s[kb][reg] = -1e30f;
            }
            mt_[reg] = fmaxf(fmaxf(s[0][reg], s[1][reg]), fmaxf(s[2][reg], s[3][reg]));
        }
#pragma unroll
        for (int off = 1; off < 16; off <<= 1)
#pragma unroll
            for (int reg = 0; reg < 4; reg++) mt_[reg] = fmaxf(mt_[reg], __shfl_xor(mt_[reg], off));

        float alpha[4], rs[4];
#pragma unroll
        for (int reg = 0; reg < 4; reg++) {
            float mn = fmaxf(m_r[reg], mt_[reg]);
            alpha[reg] = __builtin_amdgcn_exp2f(m_r[reg] - mn);
            m_r[reg] = mn;
            rs[reg] = 0.f;
        }
#pragma unroll
        for (int kb = 0; kb < 4; kb++)
#pragma unroll
            for (int reg = 0; reg < 4; reg++) {
                float p = __builtin_amdgcn_exp2f(s[kb][reg] - m_r[reg]);
                u16 pb = f2bf(p);
                ps[wave][(quad * 4 + reg) * 72 + kb * 16 + c16] = pb;
                rs[reg] += bf2f(pb);
            }
#pragma unroll
        for (int off = 1; off < 16; off <<= 1)
#pragma unroll
            for (int reg = 0; reg < 4; reg++) rs[reg] += __shfl_xor(rs[reg], off);
#pragma unroll
        for (int reg = 0; reg < 4; reg++) l_r[reg] = l_r[reg] * alpha[reg] + rs[reg];
#pragma unroll
        for (int dblk = 0; dblk < 4; dblk++)
#pragma unroll
            for (int reg = 0; reg < 4; reg++) acc[dblk][reg] *= alpha[reg];

        // PV: A = P (wave-local ps, same-wave ds ordering), B = Vt
#pragma unroll
        for (int js = 0; js < 2; js++) {
            frag_ab pf = *(const frag_ab*)&ps[wave][c16 * 72 + js * 32 + quad * 8];
#pragma unroll
            for (int dblk = 0; dblk < 4; dblk++) {
                frag_ab vf = *(const frag_ab*)&Vt[(dblk * 16 + c16) * 72 + js * 32 + quad * 8];
                acc[dblk] = __builtin_amdgcn_mfma_f32_16x16x32_bf16(pf, vf, acc[dblk], 0, 0, 0);
            }
        }
    }

    float inv[4];
#pragma unroll
    for (int reg = 0; reg < 4; reg++) inv[reg] = 1.f / l_r[reg];
#pragma unroll
    for (int dblk = 0; dblk < 4; dblk++)
#pragma unroll
        for (int reg = 0; reg < 4; reg++)
            out[(size_t)(b * SEQ + qw0 + quad * 4 + reg) * 1024 + h * 64 + dblk * 16 + c16] =
                f2bf(acc[dblk][reg] * inv[reg]);
}

extern "C" void kernel_launch(void* const* d_in, const int* in_sizes, int n_in,
                              void* d_out, int out_size, void* d_ws, size_t ws_size,
                              hipStream_t stream) {
    const float* x     = (const float*)d_in[0];   // [2,2048,1024]
    const float* W_qkv = (const float*)d_in[1];   // [1024,3072]
    const float* W_out = (const float*)d_in[2];   // [1024,1024]
    float* out = (float*)d_out;                   // [2,2048,1024]

    char* ws = (char*)d_ws;
    u16* xb    = (u16*)(ws);                       //  8 MB : x bf16 [4096,1024]
    u16* wqkvT = (u16*)(ws + 8388608);             //  6 MB : W_qkv^T bf16 [3072,1024] (q rows pre-scaled)
    u16* woutT = (u16*)(ws + 14680064);            //  2 MB : W_out^T bf16 [1024,1024]
    u16* qkvb  = (u16*)(ws + 16777216);            // 24 MB : qkv bf16 [4096,3072]
    u16* attnb = (u16*)(ws + 41943040);            //  8 MB : attn out bf16 [4096,1024]

    const float QSCALE = 0.125f * 1.4426950408889634f;  // 1/sqrt(64) * log2(e)

    {
        int n4 = NROWS * D_MODEL / 4;
        cast_kernel<<<(n4 + 255) / 256, 256, 0, stream>>>((const float4*)x, (ushort4*)xb, n4);
        transpose_cast<<<dim3(3 * D_MODEL / 32, D_MODEL / 32), dim3(32, 8), 0, stream>>>(
            W_qkv, wqkvT, D_MODEL, 3 * D_MODEL, D_MODEL, QSCALE);
        transpose_cast<<<dim3(D_MODEL / 32, D_MODEL / 32), dim3(32, 8), 0, stream>>>(
            W_out, woutT, D_MODEL, D_MODEL, 0, 1.0f);
    }
    // qkv = x @ W_qkv  [4096,3072] bf16 — BM=128, grid 24x32 = 768 blocks (3/CU)
    gemm_bk64<true, 128><<<dim3(3 * D_MODEL / 128, NROWS / 128), 256, 0, stream>>>(
        xb, wqkvT, qkvb, NROWS, 3 * D_MODEL, D_MODEL);
    attn_kernel<<<BATCH * N_HEADS * (SEQ / 64), 256, 0, stream>>>(qkvb, attnb);
    // out = attn @ W_out -> fp32 — BM=64, grid 8x64 = 512 blocks (2/CU)
    gemm_bk64<false, 64><<<dim3(D_MODEL / 128, NROWS / 64), 256, 0, stream>>>(
        attnb, woutT, out, NROWS, D_MODEL, D_MODEL);
}

// Round 4
// 157.191 us; speedup vs baseline: 3.6335x; 1.0065x over previous
//
#include <hip/hip_runtime.h>

typedef unsigned short u16;
typedef unsigned int u32;

#define D_MODEL 1024
#define N_HEADS 16
#define D_HEAD 64
#define WIN 256
#define SEQ 2048
#define BATCH 2
#define NROWS (BATCH*SEQ)          // 4096 token rows

typedef short frag_ab __attribute__((ext_vector_type(8)));   // 8 bf16 (4 VGPRs)
typedef float frag_cd __attribute__((ext_vector_type(4)));   // 4 fp32
typedef u16 u16x8 __attribute__((ext_vector_type(8)));

__device__ __forceinline__ u16 f2bf(float f) {
    union { float f; u32 u; } x; x.f = f;
    u32 r = x.u + 0x7fffu + ((x.u >> 16) & 1u);   // RNE
    return (u16)(r >> 16);
}
__device__ __forceinline__ float bf2f(u16 v) {
    union { u32 u; float f; } x; x.u = ((u32)v) << 16; return x.f;
}

__device__ __forceinline__ void load_lds16(const void* g, void* l) {
    __builtin_amdgcn_global_load_lds(
        (const __attribute__((address_space(1))) void*)g,
        (__attribute__((address_space(3))) void*)l, 16, 0, 0);
}

// ---------------- merged prep: cast x + transpose-cast both weights ----------------
// blocks [0,4096): cast x (1 float4/thread)
// blocks [4096,7168): transpose W_qkv [1024,3072] -> [3072,1024] (q rows *QSCALE)
// blocks [7168,8192): transpose W_out [1024,1024] -> [1024,1024]
__device__ __forceinline__ void transpose_tile(const float* __restrict__ W, u16* __restrict__ WT,
                                               int K, int N, int n0, int k0,
                                               int scale_rows, float scale) {
    __shared__ float tile[32][33];
    int x = threadIdx.x & 31, y = threadIdx.x >> 5;   // 32 x 8
#pragma unroll
    for (int r = 0; r < 4; r++)
        tile[y + 8 * r][x] = W[(size_t)(k0 + y + 8 * r) * N + n0 + x];
    __syncthreads();
#pragma unroll
    for (int r = 0; r < 4; r++) {
        int nrow = n0 + y + 8 * r;
        float v = tile[x][y + 8 * r];
        if (nrow < scale_rows) v *= scale;
        WT[(size_t)nrow * K + k0 + x] = f2bf(v);
    }
}

__global__ __launch_bounds__(256) void prep_kernel(const float* __restrict__ x,
                                                   const float* __restrict__ W_qkv,
                                                   const float* __restrict__ W_out,
                                                   u16* __restrict__ xb,
                                                   u16* __restrict__ wqkvT,
                                                   u16* __restrict__ woutT,
                                                   float qscale) {
    const int bid = blockIdx.x;
    if (bid < 4096) {
        int idx = bid * 256 + threadIdx.x;
        float4 v = ((const float4*)x)[idx];
        ushort4 o;
        o.x = f2bf(v.x); o.y = f2bf(v.y); o.z = f2bf(v.z); o.w = f2bf(v.w);
        ((ushort4*)xb)[idx] = o;
    } else if (bid < 4096 + 3072) {
        int t = bid - 4096;                       // N=3072: 96 x 32 tiles
        transpose_tile(W_qkv, wqkvT, D_MODEL, 3 * D_MODEL, (t % 96) * 32, (t / 96) * 32,
                       D_MODEL, qscale);
    } else {
        int t = bid - 7168;                       // N=1024: 32 x 32 tiles
        transpose_tile(W_out, woutT, D_MODEL, D_MODEL, (t % 32) * 32, (t / 32) * 32, 0, 1.0f);
    }
}

// ---------------- bf16 GEMM: C[M,N(tile 128)] = A[M,K] * BT[N,K]^T, BK=64 ----------------
// Staging: XOR-chunk swizzle on the global fetch side (LDS dest stays base+lane*16).
// BF16_OUT epilogue: LDS transpose -> coalesced dwordx4 stores.
template <bool BF16_OUT, int BM>
__global__ __launch_bounds__(256) void gemm_bk64(const u16* __restrict__ A,
                                                 const u16* __restrict__ BT,
                                                 void* __restrict__ C,
                                                 int M, int N, int K) {
    constexpr int MWAVE = BM / 2;      // rows per wave-pair group
    constexpr int MT = BM / 32;        // m-tiles per wave (4 or 2)
    __shared__ union SMem {
        struct { u16 As[BM * 64]; u16 Bs[128 * 64]; } s;
        u16 cs[BF16_OUT ? BM * 136 : 1];          // epilogue transpose tile (bf16 path)
    } sm;
    const int tid = threadIdx.x;
    const int m0 = blockIdx.y * BM, n0 = blockIdx.x * 128;
    const int wave = tid >> 6, lane = tid & 63;
    const int wm = (wave >> 1) * MWAVE, wn = (wave & 1) * 64;
    const int lrow = lane & 15, quad = lane >> 4;

    frag_cd acc[MT][4] = {};

    const int r0 = tid >> 3;                   // 0..31
    const int w  = (tid & 7) ^ (r0 & 7);       // swizzled source chunk
    const u16* aP = A  + (size_t)(m0 + r0) * K + w * 8;
    const u16* bP = BT + (size_t)(n0 + r0) * K + w * 8;

    for (int k0 = 0; k0 < K; k0 += 64) {
        __syncthreads();
#pragma unroll
        for (int u = 0; u < BM / 32; u++)
            load_lds16(aP + (size_t)(32 * u) * K + k0, &sm.s.As[(tid + 256 * u) * 8]);
#pragma unroll
        for (int u = 0; u < 4; u++)
            load_lds16(bP + (size_t)(32 * u) * K + k0, &sm.s.Bs[(tid + 256 * u) * 8]);
        __syncthreads();

#pragma unroll
        for (int ko = 0; ko < 2; ko++) {
            const int csel = ((ko * 4 + quad) ^ (lrow & 7)) * 8;
            frag_ab af[MT], bf[4];
#pragma unroll
            for (int t = 0; t < MT; t++)
                af[t] = *(const frag_ab*)&sm.s.As[(wm + t * 16 + lrow) * 64 + csel];
#pragma unroll
            for (int t = 0; t < 4; t++)
                bf[t] = *(const frag_ab*)&sm.s.Bs[(wn + t * 16 + lrow) * 64 + csel];
#pragma unroll
            for (int mt = 0; mt < MT; mt++)
#pragma unroll
                for (int nt = 0; nt < 4; nt++)
                    acc[mt][nt] = __builtin_amdgcn_mfma_f32_16x16x32_bf16(af[mt], bf[nt], acc[mt][nt], 0, 0, 0);
        }
    }

    if constexpr (BF16_OUT) {
        // phase 1: C-frags (col=lane&15, row=quad*4+reg [m89]) -> LDS, stride 136 u16
        __syncthreads();                        // all waves done reading As/Bs
#pragma unroll
        for (int mt = 0; mt < MT; mt++)
#pragma unroll
            for (int nt = 0; nt < 4; nt++) {
                int col = wn + nt * 16 + lrow;
#pragma unroll
                for (int r = 0; r < 4; r++)
                    sm.cs[(wm + mt * 16 + quad * 4 + r) * 136 + col] = f2bf(acc[mt][nt][r]);
            }
        __syncthreads();
        // phase 2: coalesced read-back + dwordx4 stores (4 full rows per wave per instr)
        const int cc = tid & 15, rb = tid >> 4;
#pragma unroll
        for (int i = 0; i < BM / 16; i++) {
            int row = rb + 16 * i;
            u16x8 vv = *(const u16x8*)&sm.cs[row * 136 + cc * 8];
            *(u16x8*)((u16*)C + (size_t)(m0 + row) * N + n0 + cc * 8) = vv;
        }
    } else {
        // f32 path: dword stores (16-lane x 64 B segments) — acceptable
#pragma unroll
        for (int mt = 0; mt < MT; mt++)
#pragma unroll
            for (int nt = 0; nt < 4; nt++) {
                int col = n0 + wn + nt * 16 + lrow;
#pragma unroll
                for (int r = 0; r < 4; r++) {
                    int row = m0 + wm + mt * 16 + quad * 4 + r;
                    ((float*)C)[(size_t)row * N + col] = acc[mt][nt][r];
                }
            }
    }
}

// ---------------- MFMA flash attention (sliding window) ----------------
// qkv [B*S, 3072] bf16 (q cols scaled by SCALE*log2e), out [B*S, 1024] bf16.
// One workgroup = 64 q-rows of one (b,h); 4 waves x 16 rows. K-tiles of 64
// keys iterated in DESCENDING j (first tile contains each row's diagonal).
__global__ __launch_bounds__(256) void attn_kernel(const u16* __restrict__ qkv, u16* __restrict__ out) {
    __shared__ u16 Ks[64 * 64];          // XOR-chunk-swizzled: chunk c of row r stored at c^(r&7)
    __shared__ u16 Vt[64 * 72];          // Vt[d][j], row pad +8
    __shared__ u16 ps[4][16 * 72];       // per-wave P tile, row pad +8

    const int tid = threadIdx.x;
    const int wave = tid >> 6, lane = tid & 63;
    const int quad = lane >> 4, c16 = lane & 15;

    const int qc = blockIdx.x & 31;
    const int h  = (blockIdx.x >> 5) & 15;
    const int b  = blockIdx.x >> 9;
    const int q0 = qc * 64;
    const int qw0 = q0 + wave * 16;

    frag_ab qf[2];
    {
        const u16* qrow = qkv + (size_t)(b * SEQ + qw0 + c16) * 3072 + h * 64;
        qf[0] = *(const frag_ab*)(qrow + quad * 8);
        qf[1] = *(const frag_ab*)(qrow + 32 + quad * 8);
    }

    float m_r[4], l_r[4];
    frag_cd acc[4] = {};
#pragma unroll
    for (int r = 0; r < 4; r++) { m_r[r] = -1e30f; l_r[r] = 0.f; }

    const int ntiles = qc < 4 ? qc + 1 : 5;

    const int krow = wave * 16 + (lane >> 3);
    const int kchunk = (lane & 7) ^ (lane >> 3);
    const int vj2 = (tid & 31) * 2, vd8 = tid >> 5;

    for (int t = 0; t < ntiles; t++) {
        const int j0 = q0 - 64 * t;
        __syncthreads();
        {
            const u16* g = qkv + (size_t)(b * SEQ + j0 + krow) * 3072 + 1024 + h * 64 + kchunk * 8;
            load_lds16(g,            &Ks[krow * 64 + (lane & 7) * 8]);
            load_lds16(g + 8 * 3072, &Ks[(krow + 8) * 64 + (lane & 7) * 8]);
        }
        {
            const u16* g = qkv + (size_t)(b * SEQ + j0 + vj2) * 3072 + 2048 + h * 64 + vd8 * 8;
            u16x8 va = *(const u16x8*)g;
            u16x8 vb = *(const u16x8*)(g + 3072);
#pragma unroll
            for (int dd = 0; dd < 8; dd++)
                *(u32*)&Vt[(vd8 * 8 + dd) * 72 + vj2] = (u32)va[dd] | ((u32)vb[dd] << 16);
        }
        __syncthreads();

        frag_cd s[4] = {};
#pragma unroll
        for (int kb = 0; kb < 4; kb++) {
            frag_ab kf0 = *(const frag_ab*)&Ks[(kb * 16 + c16) * 64 + ((quad    ) ^ (c16 & 7)) * 8];
            frag_ab kf1 = *(const frag_ab*)&Ks[(kb * 16 + c16) * 64 + ((4 + quad) ^ (c16 & 7)) * 8];
            s[kb] = __builtin_amdgcn_mfma_f32_16x16x32_bf16(qf[0], kf0, s[kb], 0, 0, 0);
            s[kb] = __builtin_amdgcn_mfma_f32_16x16x32_bf16(qf[1], kf1, s[kb], 0, 0, 0);
        }

        float mt_[4];
#pragma unroll
        for (int reg = 0; reg < 4; reg++) {
            const int i = qw0 + quad * 4 + reg;
#pragma unroll
            for (int kb = 0; kb < 4; kb++) {
                const int j = j0 + kb * 16 + c16;
                if (j > i || j + WIN <= i) s[kb][reg] = -1e30f;
            }
            mt_[reg] = fmaxf(fmaxf(s[0][reg], s[1][reg]), fmaxf(s[2][reg], s[3][reg]));
        }
#pragma unroll
        for (int off = 1; off < 16; off <<= 1)
#pragma unroll
            for (int reg = 0; reg < 4; reg++) mt_[reg] = fmaxf(mt_[reg], __shfl_xor(mt_[reg], off));

        float alpha[4], rs[4];
#pragma unroll
        for (int reg = 0; reg < 4; reg++) {
            float mn = fmaxf(m_r[reg], mt_[reg]);
            alpha[reg] = __builtin_amdgcn_exp2f(m_r[reg] - mn);
            m_r[reg] = mn;
            rs[reg] = 0.f;
        }
#pragma unroll
        for (int kb = 0; kb < 4; kb++)
#pragma unroll
            for (int reg = 0; reg < 4; reg++) {
                float p = __builtin_amdgcn_exp2f(s[kb][reg] - m_r[reg]);
                u16 pb = f2bf(p);
                ps[wave][(quad * 4 + reg) * 72 + kb * 16 + c16] = pb;
                rs[reg] += bf2f(pb);
            }
#pragma unroll
        for (int off = 1; off < 16; off <<= 1)
#pragma unroll
            for (int reg = 0; reg < 4; reg++) rs[reg] += __shfl_xor(rs[reg], off);
#pragma unroll
        for (int reg = 0; reg < 4; reg++) l_r[reg] = l_r[reg] * alpha[reg] + rs[reg];
#pragma unroll
        for (int dblk = 0; dblk < 4; dblk++)
#pragma unroll
            for (int reg = 0; reg < 4; reg++) acc[dblk][reg] *= alpha[reg];

#pragma unroll
        for (int js = 0; js < 2; js++) {
            frag_ab pf = *(const frag_ab*)&ps[wave][c16 * 72 + js * 32 + quad * 8];
#pragma unroll
            for (int dblk = 0; dblk < 4; dblk++) {
                frag_ab vf = *(const frag_ab*)&Vt[(dblk * 16 + c16) * 72 + js * 32 + quad * 8];
                acc[dblk] = __builtin_amdgcn_mfma_f32_16x16x32_bf16(pf, vf, acc[dblk], 0, 0, 0);
            }
        }
    }

    float inv[4];
#pragma unroll
    for (int reg = 0; reg < 4; reg++) inv[reg] = 1.f / l_r[reg];
#pragma unroll
    for (int dblk = 0; dblk < 4; dblk++)
#pragma unroll
        for (int reg = 0; reg < 4; reg++)
            out[(size_t)(b * SEQ + qw0 + quad * 4 + reg) * 1024 + h * 64 + dblk * 16 + c16] =
                f2bf(acc[dblk][reg] * inv[reg]);
}

extern "C" void kernel_launch(void* const* d_in, const int* in_sizes, int n_in,
                              void* d_out, int out_size, void* d_ws, size_t ws_size,
                              hipStream_t stream) {
    const float* x     = (const float*)d_in[0];   // [2,2048,1024]
    const float* W_qkv = (const float*)d_in[1];   // [1024,3072]
    const float* W_out = (const float*)d_in[2];   // [1024,1024]
    float* out = (float*)d_out;                   // [2,2048,1024]

    char* ws = (char*)d_ws;
    u16* xb    = (u16*)(ws);                       //  8 MB : x bf16 [4096,1024]
    u16* wqkvT = (u16*)(ws + 8388608);             //  6 MB : W_qkv^T bf16 [3072,1024] (q rows pre-scaled)
    u16* woutT = (u16*)(ws + 14680064);            //  2 MB : W_out^T bf16 [1024,1024]
    u16* qkvb  = (u16*)(ws + 16777216);            // 24 MB : qkv bf16 [4096,3072]
    u16* attnb = (u16*)(ws + 41943040);            //  8 MB : attn out bf16 [4096,1024]

    const float QSCALE = 0.125f * 1.4426950408889634f;  // 1/sqrt(64) * log2(e)

    prep_kernel<<<8192, 256, 0, stream>>>(x, W_qkv, W_out, xb, wqkvT, woutT, QSCALE);
    gemm_bk64<true, 128><<<dim3(3 * D_MODEL / 128, NROWS / 128), 256, 0, stream>>>(
        xb, wqkvT, qkvb, NROWS, 3 * D_MODEL, D_MODEL);
    attn_kernel<<<BATCH * N_HEADS * (SEQ / 64), 256, 0, stream>>>(qkvb, attnb);
    gemm_bk64<false, 64><<<dim3(D_MODEL / 128, NROWS / 64), 256, 0, stream>>>(
        attnb, woutT, out, NROWS, D_MODEL, D_MODEL);
}

// Round 5
// 155.088 us; speedup vs baseline: 3.6828x; 1.0136x over previous
//
#include <hip/hip_runtime.h>

typedef unsigned short u16;
typedef unsigned int u32;

#define D_MODEL 1024
#define N_HEADS 16
#define D_HEAD 64
#define WIN 256
#define SEQ 2048
#define BATCH 2
#define NROWS (BATCH*SEQ)          // 4096 token rows

typedef short frag_ab __attribute__((ext_vector_type(8)));   // 8 bf16 (4 VGPRs)
typedef float frag_cd __attribute__((ext_vector_type(4)));   // 4 fp32
typedef u16 u16x8 __attribute__((ext_vector_type(8)));

__device__ __forceinline__ u16 f2bf(float f) {
    union { float f; u32 u; } x; x.f = f;
    u32 r = x.u + 0x7fffu + ((x.u >> 16) & 1u);   // RNE
    return (u16)(r >> 16);
}
__device__ __forceinline__ float bf2f(u16 v) {
    union { u32 u; float f; } x; x.u = ((u32)v) << 16; return x.f;
}

__device__ __forceinline__ void load_lds16(const void* g, void* l) {
    __builtin_amdgcn_global_load_lds(
        (const __attribute__((address_space(1))) void*)g,
        (__attribute__((address_space(3))) void*)l, 16, 0, 0);
}

// ---------------- merged prep: cast x + transpose-cast both weights ----------------
__device__ __forceinline__ void transpose_tile(const float* __restrict__ W, u16* __restrict__ WT,
                                               int K, int N, int n0, int k0,
                                               int scale_rows, float scale) {
    __shared__ float tile[32][33];
    int x = threadIdx.x & 31, y = threadIdx.x >> 5;   // 32 x 8
#pragma unroll
    for (int r = 0; r < 4; r++)
        tile[y + 8 * r][x] = W[(size_t)(k0 + y + 8 * r) * N + n0 + x];
    __syncthreads();
#pragma unroll
    for (int r = 0; r < 4; r++) {
        int nrow = n0 + y + 8 * r;
        float v = tile[x][y + 8 * r];
        if (nrow < scale_rows) v *= scale;
        WT[(size_t)nrow * K + k0 + x] = f2bf(v);
    }
}

__global__ __launch_bounds__(256) void prep_kernel(const float* __restrict__ x,
                                                   const float* __restrict__ W_qkv,
                                                   const float* __restrict__ W_out,
                                                   u16* __restrict__ xb,
                                                   u16* __restrict__ wqkvT,
                                                   u16* __restrict__ woutT,
                                                   float qscale) {
    const int bid = blockIdx.x;
    if (bid < 4096) {
        int idx = bid * 256 + threadIdx.x;
        float4 v = ((const float4*)x)[idx];
        ushort4 o;
        o.x = f2bf(v.x); o.y = f2bf(v.y); o.z = f2bf(v.z); o.w = f2bf(v.w);
        ((ushort4*)xb)[idx] = o;
    } else if (bid < 4096 + 3072) {
        int t = bid - 4096;                       // N=3072: 96 x 32 tiles
        transpose_tile(W_qkv, wqkvT, D_MODEL, 3 * D_MODEL, (t % 96) * 32, (t / 96) * 32,
                       D_MODEL, qscale);
    } else {
        int t = bid - 7168;                       // N=1024: 32 x 32 tiles
        transpose_tile(W_out, woutT, D_MODEL, D_MODEL, (t % 32) * 32, (t / 32) * 32, 0, 1.0f);
    }
}

// ---------------- bf16 GEMM: C[M,N(tile 128)] = A[M,K] * BT[N,K]^T, BK=64 ----------------
template <bool BF16_OUT, int BM>
__global__ __launch_bounds__(256) void gemm_bk64(const u16* __restrict__ A,
                                                 const u16* __restrict__ BT,
                                                 void* __restrict__ C,
                                                 int M, int N, int K) {
    constexpr int MWAVE = BM / 2;      // rows per wave-pair group
    constexpr int MT = BM / 32;        // m-tiles per wave (4 or 2)
    __shared__ union SMem {
        struct { u16 As[BM * 64]; u16 Bs[128 * 64]; } s;
        u16 cs[BF16_OUT ? BM * 136 : 1];          // epilogue transpose tile (bf16 path)
    } sm;
    const int tid = threadIdx.x;
    const int m0 = blockIdx.y * BM, n0 = blockIdx.x * 128;
    const int wave = tid >> 6, lane = tid & 63;
    const int wm = (wave >> 1) * MWAVE, wn = (wave & 1) * 64;
    const int lrow = lane & 15, quad = lane >> 4;

    frag_cd acc[MT][4] = {};

    const int r0 = tid >> 3;                   // 0..31
    const int w  = (tid & 7) ^ (r0 & 7);       // swizzled source chunk
    const u16* aP = A  + (size_t)(m0 + r0) * K + w * 8;
    const u16* bP = BT + (size_t)(n0 + r0) * K + w * 8;

    for (int k0 = 0; k0 < K; k0 += 64) {
        __syncthreads();
#pragma unroll
        for (int u = 0; u < BM / 32; u++)
            load_lds16(aP + (size_t)(32 * u) * K + k0, &sm.s.As[(tid + 256 * u) * 8]);
#pragma unroll
        for (int u = 0; u < 4; u++)
            load_lds16(bP + (size_t)(32 * u) * K + k0, &sm.s.Bs[(tid + 256 * u) * 8]);
        __syncthreads();

#pragma unroll
        for (int ko = 0; ko < 2; ko++) {
            const int csel = ((ko * 4 + quad) ^ (lrow & 7)) * 8;
            frag_ab af[MT], bf[4];
#pragma unroll
            for (int t = 0; t < MT; t++)
                af[t] = *(const frag_ab*)&sm.s.As[(wm + t * 16 + lrow) * 64 + csel];
#pragma unroll
            for (int t = 0; t < 4; t++)
                bf[t] = *(const frag_ab*)&sm.s.Bs[(wn + t * 16 + lrow) * 64 + csel];
#pragma unroll
            for (int mt = 0; mt < MT; mt++)
#pragma unroll
                for (int nt = 0; nt < 4; nt++)
                    acc[mt][nt] = __builtin_amdgcn_mfma_f32_16x16x32_bf16(af[mt], bf[nt], acc[mt][nt], 0, 0, 0);
        }
    }

    if constexpr (BF16_OUT) {
        __syncthreads();
#pragma unroll
        for (int mt = 0; mt < MT; mt++)
#pragma unroll
            for (int nt = 0; nt < 4; nt++) {
                int col = wn + nt * 16 + lrow;
#pragma unroll
                for (int r = 0; r < 4; r++)
                    sm.cs[(wm + mt * 16 + quad * 4 + r) * 136 + col] = f2bf(acc[mt][nt][r]);
            }
        __syncthreads();
        const int cc = tid & 15, rb = tid >> 4;
#pragma unroll
        for (int i = 0; i < BM / 16; i++) {
            int row = rb + 16 * i;
            u16x8 vv = *(const u16x8*)&sm.cs[row * 136 + cc * 8];
            *(u16x8*)((u16*)C + (size_t)(m0 + row) * N + n0 + cc * 8) = vv;
        }
    } else {
#pragma unroll
        for (int mt = 0; mt < MT; mt++)
#pragma unroll
            for (int nt = 0; nt < 4; nt++) {
                int col = n0 + wn + nt * 16 + lrow;
#pragma unroll
                for (int r = 0; r < 4; r++) {
                    int row = m0 + wm + mt * 16 + quad * 4 + r;
                    ((float*)C)[(size_t)row * N + col] = acc[mt][nt][r];
                }
            }
    }
}

// ---------------- MFMA flash attention (sliding window), pipelined ----------------
// qkv [B*S, 3072] bf16 (q cols scaled by SCALE*log2e), out [B*S, 1024] bf16.
// One workgroup = 64 q-rows of one (b,h); 4 waves x 16 rows. Tiles of 64 keys,
// DESCENDING j (t=0 holds the diagonal -> running max valid from the start).
// Pipeline: K double-buffered via global_load_lds issued right after the top
// barrier (in flight across the whole tile compute); V prefetched into regs
// early, written to its single LDS buffer after an inner barrier.
// Masks exist only on t=0 (causal diag) and t=4 (window edge) — proven:
// for t=1..3, i-j ∈ [64t-63, 64t+63] ⊂ [1,255], always inside the window.
__global__ __launch_bounds__(256) void attn_kernel(const u16* __restrict__ qkv, u16* __restrict__ out) {
    __shared__ u16 Ks[2][64 * 64];       // XOR-chunk-swizzled: chunk c of row r at c^(r&7)
    __shared__ u16 Vt[64 * 72];          // Vt[d][j], row pad +8 (single buffer)
    __shared__ u16 ps[4][16 * 72];       // per-wave P tile, row pad +8

    const int tid = threadIdx.x;
    const int wave = tid >> 6, lane = tid & 63;
    const int quad = lane >> 4, c16 = lane & 15;

    const int qc = blockIdx.x & 31;
    const int h  = (blockIdx.x >> 5) & 15;
    const int b  = blockIdx.x >> 9;
    const int q0 = qc * 64;
    const int qw0 = q0 + wave * 16;

    frag_ab qf[2];
    {
        const u16* qrow = qkv + (size_t)(b * SEQ + qw0 + c16) * 3072 + h * 64;
        qf[0] = *(const frag_ab*)(qrow + quad * 8);
        qf[1] = *(const frag_ab*)(qrow + 32 + quad * 8);
    }

    float m_r[4], l_r[4];
    frag_cd acc[4] = {};

    const int ntiles = qc < 4 ? qc + 1 : 5;

    const int krow = wave * 16 + (lane >> 3);
    const int kchunk = (lane & 7) ^ (lane >> 3);
    const int vj2 = (tid & 31) * 2, vd8 = tid >> 5;

    const u16* kbase = qkv + (size_t)(b * SEQ + krow) * 3072 + 1024 + h * 64 + kchunk * 8;
    const u16* vbase = qkv + (size_t)(b * SEQ + vj2) * 3072 + 2048 + h * 64 + vd8 * 8;

    // prologue: stage tile 0
    u16x8 va, vb;
    {
        const u16* g = kbase + (size_t)q0 * 3072;
        load_lds16(g,            &Ks[0][krow * 64 + (lane & 7) * 8]);
        load_lds16(g + 8 * 3072, &Ks[0][(krow + 8) * 64 + (lane & 7) * 8]);
        const u16* gv = vbase + (size_t)q0 * 3072;
        va = *(const u16x8*)gv;
        vb = *(const u16x8*)(gv + 3072);
#pragma unroll
        for (int dd = 0; dd < 8; dd++)
            *(u32*)&Vt[(vd8 * 8 + dd) * 72 + vj2] = (u32)va[dd] | ((u32)vb[dd] << 16);
    }

    for (int t = 0; t < ntiles; t++) {
        const int cur = t & 1, nxt = cur ^ 1;
        const int j0 = q0 - 64 * t;
        __syncthreads();                 // Ks[cur] + Vt staged & visible
        const bool pre = (t + 1 < ntiles);
        if (pre) {                       // prefetch t+1: K -> LDS[nxt] (async), V -> regs
            const u16* g = kbase + (size_t)(j0 - 64) * 3072;
            load_lds16(g,            &Ks[nxt][krow * 64 + (lane & 7) * 8]);
            load_lds16(g + 8 * 3072, &Ks[nxt][(krow + 8) * 64 + (lane & 7) * 8]);
            const u16* gv = vbase + (size_t)(j0 - 64) * 3072;
            va = *(const u16x8*)gv;
            vb = *(const u16x8*)(gv + 3072);
        }

        // QK^T
        frag_cd s[4] = {};
#pragma unroll
        for (int kb = 0; kb < 4; kb++) {
            frag_ab kf0 = *(const frag_ab*)&Ks[cur][(kb * 16 + c16) * 64 + ((quad    ) ^ (c16 & 7)) * 8];
            frag_ab kf1 = *(const frag_ab*)&Ks[cur][(kb * 16 + c16) * 64 + ((4 + quad) ^ (c16 & 7)) * 8];
            s[kb] = __builtin_amdgcn_mfma_f32_16x16x32_bf16(qf[0], kf0, s[kb], 0, 0, 0);
            s[kb] = __builtin_amdgcn_mfma_f32_16x16x32_bf16(qf[1], kf1, s[kb], 0, 0, 0);
        }

        // masks: t=0 diag only, t=4 window only, interior none
        if (t == 0) {
#pragma unroll
            for (int reg = 0; reg < 4; reg++) {
                const int i = qw0 + quad * 4 + reg;
#pragma unroll
                for (int kb = 0; kb < 4; kb++)
                    if (q0 + kb * 16 + c16 > i) s[kb][reg] = -1e30f;
            }
        } else if (t == 4) {
#pragma unroll
            for (int reg = 0; reg < 4; reg++) {
                const int i = qw0 + quad * 4 + reg;
#pragma unroll
                for (int kb = 0; kb < 4; kb++)
                    if (j0 + kb * 16 + c16 + WIN <= i) s[kb][reg] = -1e30f;
            }
        }

        float mt_[4];
#pragma unroll
        for (int reg = 0; reg < 4; reg++)
            mt_[reg] = fmaxf(fmaxf(s[0][reg], s[1][reg]), fmaxf(s[2][reg], s[3][reg]));
#pragma unroll
        for (int off = 1; off < 16; off <<= 1)
#pragma unroll
            for (int reg = 0; reg < 4; reg++) mt_[reg] = fmaxf(mt_[reg], __shfl_xor(mt_[reg], off));

        float alpha[4];
        if (t == 0) {
#pragma unroll
            for (int reg = 0; reg < 4; reg++) m_r[reg] = mt_[reg];
        } else {
#pragma unroll
            for (int reg = 0; reg < 4; reg++) {
                float mn = fmaxf(m_r[reg], mt_[reg]);
                alpha[reg] = __builtin_amdgcn_exp2f(m_r[reg] - mn);
                m_r[reg] = mn;
            }
        }

        float rs[4] = {0.f, 0.f, 0.f, 0.f};
#pragma unroll
        for (int kb = 0; kb < 4; kb++)
#pragma unroll
            for (int reg = 0; reg < 4; reg++) {
                float p = __builtin_amdgcn_exp2f(s[kb][reg] - m_r[reg]);
                union { float f; u32 u; } pu; pu.f = p;
                ps[wave][(quad * 4 + reg) * 72 + kb * 16 + c16] = (u16)(pu.u >> 16);  // RTZ
                rs[reg] += p;
            }
#pragma unroll
        for (int off = 1; off < 16; off <<= 1)
#pragma unroll
            for (int reg = 0; reg < 4; reg++) rs[reg] += __shfl_xor(rs[reg], off);

        if (t == 0) {
#pragma unroll
            for (int reg = 0; reg < 4; reg++) l_r[reg] = rs[reg];
        } else {
#pragma unroll
            for (int reg = 0; reg < 4; reg++) l_r[reg] = l_r[reg] * alpha[reg] + rs[reg];
#pragma unroll
            for (int dblk = 0; dblk < 4; dblk++)
#pragma unroll
                for (int reg = 0; reg < 4; reg++) acc[dblk][reg] *= alpha[reg];
        }

        // PV
#pragma unroll
        for (int js = 0; js < 2; js++) {
            frag_ab pf = *(const frag_ab*)&ps[wave][c16 * 72 + js * 32 + quad * 8];
#pragma unroll
            for (int dblk = 0; dblk < 4; dblk++) {
                frag_ab vf = *(const frag_ab*)&Vt[(dblk * 16 + c16) * 72 + js * 32 + quad * 8];
                acc[dblk] = __builtin_amdgcn_mfma_f32_16x16x32_bf16(pf, vf, acc[dblk], 0, 0, 0);
            }
        }

        if (pre) {
            __syncthreads();             // all waves done with PV(t) -> Vt overwrite safe
#pragma unroll
            for (int dd = 0; dd < 8; dd++)
                *(u32*)&Vt[(vd8 * 8 + dd) * 72 + vj2] = (u32)va[dd] | ((u32)vb[dd] << 16);
        }
    }

    float inv[4];
#pragma unroll
    for (int reg = 0; reg < 4; reg++) inv[reg] = 1.f / l_r[reg];
#pragma unroll
    for (int dblk = 0; dblk < 4; dblk++)
#pragma unroll
        for (int reg = 0; reg < 4; reg++)
            out[(size_t)(b * SEQ + qw0 + quad * 4 + reg) * 1024 + h * 64 + dblk * 16 + c16] =
                f2bf(acc[dblk][reg] * inv[reg]);
}

extern "C" void kernel_launch(void* const* d_in, const int* in_sizes, int n_in,
                              void* d_out, int out_size, void* d_ws, size_t ws_size,
                              hipStream_t stream) {
    const float* x     = (const float*)d_in[0];   // [2,2048,1024]
    const float* W_qkv = (const float*)d_in[1];   // [1024,3072]
    const float* W_out = (const float*)d_in[2];   // [1024,1024]
    float* out = (float*)d_out;                   // [2,2048,1024]

    char* ws = (char*)d_ws;
    u16* xb    = (u16*)(ws);                       //  8 MB : x bf16 [4096,1024]
    u16* wqkvT = (u16*)(ws + 8388608);             //  6 MB : W_qkv^T bf16 [3072,1024] (q rows pre-scaled)
    u16* woutT = (u16*)(ws + 14680064);            //  2 MB : W_out^T bf16 [1024,1024]
    u16* qkvb  = (u16*)(ws + 16777216);            // 24 MB : qkv bf16 [4096,3072]
    u16* attnb = (u16*)(ws + 41943040);            //  8 MB : attn out bf16 [4096,1024]

    const float QSCALE = 0.125f * 1.4426950408889634f;  // 1/sqrt(64) * log2(e)

    prep_kernel<<<8192, 256, 0, stream>>>(x, W_qkv, W_out, xb, wqkvT, woutT, QSCALE);
    gemm_bk64<true, 128><<<dim3(3 * D_MODEL / 128, NROWS / 128), 256, 0, stream>>>(
        xb, wqkvT, qkvb, NROWS, 3 * D_MODEL, D_MODEL);
    attn_kernel<<<BATCH * N_HEADS * (SEQ / 64), 256, 0, stream>>>(qkvb, attnb);
    gemm_bk64<false, 64><<<dim3(D_MODEL / 128, NROWS / 64), 256, 0, stream>>>(
        attnb, woutT, out, NROWS, D_MODEL, D_MODEL);
}

// Round 6
// 154.551 us; speedup vs baseline: 3.6956x; 1.0035x over previous
//
#include <hip/hip_runtime.h>

typedef unsigned short u16;
typedef unsigned int u32;

#define D_MODEL 1024
#define N_HEADS 16
#define D_HEAD 64
#define WIN 256
#define SEQ 2048
#define BATCH 2
#define NROWS (BATCH*SEQ)          // 4096 token rows

typedef short frag_ab __attribute__((ext_vector_type(8)));   // 8 bf16 (4 VGPRs)
typedef float frag_cd __attribute__((ext_vector_type(4)));   // 4 fp32 (16x16 C/D)
typedef float f32x16 __attribute__((ext_vector_type(16)));   // 32x32 C/D
typedef u16 u16x8 __attribute__((ext_vector_type(8)));

__device__ __forceinline__ u16 f2bf(float f) {
    union { float f; u32 u; } x; x.f = f;
    u32 r = x.u + 0x7fffu + ((x.u >> 16) & 1u);   // RNE
    return (u16)(r >> 16);
}
__device__ __forceinline__ float bf2f(u16 v) {
    union { u32 u; float f; } x; x.u = ((u32)v) << 16; return x.f;
}

__device__ __forceinline__ void load_lds16(const void* g, void* l) {
    __builtin_amdgcn_global_load_lds(
        (const __attribute__((address_space(1))) void*)g,
        (__attribute__((address_space(3))) void*)l, 16, 0, 0);
}

// ---------------- merged prep: cast x + transpose-cast both weights ----------------
__device__ __forceinline__ void transpose_tile(const float* __restrict__ W, u16* __restrict__ WT,
                                               int K, int N, int n0, int k0,
                                               int scale_rows, float scale) {
    __shared__ float tile[32][33];
    int x = threadIdx.x & 31, y = threadIdx.x >> 5;   // 32 x 8
#pragma unroll
    for (int r = 0; r < 4; r++)
        tile[y + 8 * r][x] = W[(size_t)(k0 + y + 8 * r) * N + n0 + x];
    __syncthreads();
#pragma unroll
    for (int r = 0; r < 4; r++) {
        int nrow = n0 + y + 8 * r;
        float v = tile[x][y + 8 * r];
        if (nrow < scale_rows) v *= scale;
        WT[(size_t)nrow * K + k0 + x] = f2bf(v);
    }
}

__global__ __launch_bounds__(256) void prep_kernel(const float* __restrict__ x,
                                                   const float* __restrict__ W_qkv,
                                                   const float* __restrict__ W_out,
                                                   u16* __restrict__ xb,
                                                   u16* __restrict__ wqkvT,
                                                   u16* __restrict__ woutT,
                                                   float qscale) {
    const int bid = blockIdx.x;
    if (bid < 4096) {
        int idx = bid * 256 + threadIdx.x;
        float4 v = ((const float4*)x)[idx];
        ushort4 o;
        o.x = f2bf(v.x); o.y = f2bf(v.y); o.z = f2bf(v.z); o.w = f2bf(v.w);
        ((ushort4*)xb)[idx] = o;
    } else if (bid < 4096 + 3072) {
        int t = bid - 4096;                       // N=3072: 96 x 32 tiles
        transpose_tile(W_qkv, wqkvT, D_MODEL, 3 * D_MODEL, (t % 96) * 32, (t / 96) * 32,
                       D_MODEL, qscale);
    } else {
        int t = bid - 7168;                       // N=1024: 32 x 32 tiles
        transpose_tile(W_out, woutT, D_MODEL, D_MODEL, (t % 32) * 32, (t / 32) * 32, 0, 1.0f);
    }
}

// ---------------- bf16 GEMM: C[M,N(tile 128)] = A[M,K] * BT[N,K]^T, BK=64, 32x32x16 frags ----
// Staging: XOR-chunk swizzle on the global fetch side (LDS dest stays base+lane*16).
// LDS row = 64 u16 = 8 chunks of 16B; global chunk w stored at pos w^(row&7).
// Frag read for k-sub kk (16 wide): lane holds m=lane&31, k=(lane>>5)*8+j ->
// chunk c = kk*2 + (lane>>5), at swizzled pos c^(row&7); row&7 == (lane&31)&7.
// C/D layout [m74/m101]: col=lane&31, row=(reg&3)+8*(reg>>2)+4*(lane>>5).
template <bool BF16_OUT, int BM>
__global__ __launch_bounds__(256, 4) void gemm_bk64(const u16* __restrict__ A,
                                                    const u16* __restrict__ BT,
                                                    void* __restrict__ C,
                                                    int M, int N, int K) {
    constexpr int MT = BM / 64;        // 32-row m-subtiles per wave (128->2, 64->1)
    __shared__ union SMem {
        struct { u16 As[BM * 64]; u16 Bs[128 * 64]; } s;
        u16 cs[BF16_OUT ? BM * 136 : 1];          // epilogue transpose tile (bf16 path)
    } sm;
    const int tid = threadIdx.x;
    const int m0 = blockIdx.y * BM, n0 = blockIdx.x * 128;
    const int wave = tid >> 6, lane = tid & 63;
    const int wm = (wave >> 1) * (BM / 2), wn = (wave & 1) * 64;
    const int l32 = lane & 31, kh = lane >> 5;

    f32x16 acc[MT][2] = {};

    const int r0 = tid >> 3;                   // 0..31
    const int w  = (tid & 7) ^ (r0 & 7);       // swizzled source chunk
    const u16* aP = A  + (size_t)(m0 + r0) * K + w * 8;
    const u16* bP = BT + (size_t)(n0 + r0) * K + w * 8;

    for (int k0 = 0; k0 < K; k0 += 64) {
        __syncthreads();
#pragma unroll
        for (int u = 0; u < BM / 32; u++)
            load_lds16(aP + (size_t)(32 * u) * K + k0, &sm.s.As[(tid + 256 * u) * 8]);
#pragma unroll
        for (int u = 0; u < 4; u++)
            load_lds16(bP + (size_t)(32 * u) * K + k0, &sm.s.Bs[(tid + 256 * u) * 8]);
        __syncthreads();

#pragma unroll
        for (int kk = 0; kk < 4; kk++) {
            const int csel = ((kk * 2 + kh) ^ (l32 & 7)) * 8;
            frag_ab af[MT], bf[2];
#pragma unroll
            for (int t = 0; t < MT; t++)
                af[t] = *(const frag_ab*)&sm.s.As[(wm + t * 32 + l32) * 64 + csel];
#pragma unroll
            for (int t = 0; t < 2; t++)
                bf[t] = *(const frag_ab*)&sm.s.Bs[(wn + t * 32 + l32) * 64 + csel];
#pragma unroll
            for (int mt = 0; mt < MT; mt++)
#pragma unroll
                for (int nt = 0; nt < 2; nt++)
                    acc[mt][nt] = __builtin_amdgcn_mfma_f32_32x32x16_bf16(af[mt], bf[nt], acc[mt][nt], 0, 0, 0);
        }
    }

    if constexpr (BF16_OUT) {
        __syncthreads();
#pragma unroll
        for (int mt = 0; mt < MT; mt++)
#pragma unroll
            for (int nt = 0; nt < 2; nt++) {
                int col = wn + nt * 32 + l32;
#pragma unroll
                for (int reg = 0; reg < 16; reg++) {
                    int row = wm + mt * 32 + (reg & 3) + 8 * (reg >> 2) + 4 * kh;
                    sm.cs[row * 136 + col] = f2bf(acc[mt][nt][reg]);
                }
            }
        __syncthreads();
        const int cc = tid & 15, rb = tid >> 4;
#pragma unroll
        for (int i = 0; i < BM / 16; i++) {
            int row = rb + 16 * i;
            u16x8 vv = *(const u16x8*)&sm.cs[row * 136 + cc * 8];
            *(u16x8*)((u16*)C + (size_t)(m0 + row) * N + n0 + cc * 8) = vv;
        }
    } else {
        // f32 path: 32 consecutive cols/lane-group -> 2x128B segments per store
#pragma unroll
        for (int mt = 0; mt < MT; mt++)
#pragma unroll
            for (int nt = 0; nt < 2; nt++) {
                int col = n0 + wn + nt * 32 + l32;
#pragma unroll
                for (int reg = 0; reg < 16; reg++) {
                    int row = m0 + wm + mt * 32 + (reg & 3) + 8 * (reg >> 2) + 4 * kh;
                    ((float*)C)[(size_t)row * N + col] = acc[mt][nt][reg];
                }
            }
    }
}

// ---------------- MFMA flash attention (sliding window), pipelined ----------------
// qkv [B*S, 3072] bf16 (q cols scaled by SCALE*log2e), out [B*S, 1024] bf16.
// One workgroup = 64 q-rows of one (b,h); 4 waves x 16 rows. Tiles of 64 keys,
// DESCENDING j (t=0 holds the diagonal). K double-buffered via global_load_lds;
// V prefetched into regs, written to single LDS buffer after inner barrier.
__global__ __launch_bounds__(256) void attn_kernel(const u16* __restrict__ qkv, u16* __restrict__ out) {
    __shared__ u16 Ks[2][64 * 64];       // XOR-chunk-swizzled: chunk c of row r at c^(r&7)
    __shared__ u16 Vt[64 * 72];          // Vt[d][j], row pad +8 (single buffer)
    __shared__ u16 ps[4][16 * 72];       // per-wave P tile, row pad +8

    const int tid = threadIdx.x;
    const int wave = tid >> 6, lane = tid & 63;
    const int quad = lane >> 4, c16 = lane & 15;

    const int qc = blockIdx.x & 31;
    const int h  = (blockIdx.x >> 5) & 15;
    const int b  = blockIdx.x >> 9;
    const int q0 = qc * 64;
    const int qw0 = q0 + wave * 16;

    frag_ab qf[2];
    {
        const u16* qrow = qkv + (size_t)(b * SEQ + qw0 + c16) * 3072 + h * 64;
        qf[0] = *(const frag_ab*)(qrow + quad * 8);
        qf[1] = *(const frag_ab*)(qrow + 32 + quad * 8);
    }

    float m_r[4], l_r[4];
    frag_cd acc[4] = {};

    const int ntiles = qc < 4 ? qc + 1 : 5;

    const int krow = wave * 16 + (lane >> 3);
    const int kchunk = (lane & 7) ^ (lane >> 3);
    const int vj2 = (tid & 31) * 2, vd8 = tid >> 5;

    const u16* kbase = qkv + (size_t)(b * SEQ + krow) * 3072 + 1024 + h * 64 + kchunk * 8;
    const u16* vbase = qkv + (size_t)(b * SEQ + vj2) * 3072 + 2048 + h * 64 + vd8 * 8;

    u16x8 va, vb;
    {
        const u16* g = kbase + (size_t)q0 * 3072;
        load_lds16(g,            &Ks[0][krow * 64 + (lane & 7) * 8]);
        load_lds16(g + 8 * 3072, &Ks[0][(krow + 8) * 64 + (lane & 7) * 8]);
        const u16* gv = vbase + (size_t)q0 * 3072;
        va = *(const u16x8*)gv;
        vb = *(const u16x8*)(gv + 3072);
#pragma unroll
        for (int dd = 0; dd < 8; dd++)
            *(u32*)&Vt[(vd8 * 8 + dd) * 72 + vj2] = (u32)va[dd] | ((u32)vb[dd] << 16);
    }

    for (int t = 0; t < ntiles; t++) {
        const int cur = t & 1, nxt = cur ^ 1;
        const int j0 = q0 - 64 * t;
        __syncthreads();                 // Ks[cur] + Vt staged & visible
        const bool pre = (t + 1 < ntiles);
        if (pre) {                       // prefetch t+1: K -> LDS[nxt] (async), V -> regs
            const u16* g = kbase + (size_t)(j0 - 64) * 3072;
            load_lds16(g,            &Ks[nxt][krow * 64 + (lane & 7) * 8]);
            load_lds16(g + 8 * 3072, &Ks[nxt][(krow + 8) * 64 + (lane & 7) * 8]);
            const u16* gv = vbase + (size_t)(j0 - 64) * 3072;
            va = *(const u16x8*)gv;
            vb = *(const u16x8*)(gv + 3072);
        }

        frag_cd s[4] = {};
#pragma unroll
        for (int kb = 0; kb < 4; kb++) {
            frag_ab kf0 = *(const frag_ab*)&Ks[cur][(kb * 16 + c16) * 64 + ((quad    ) ^ (c16 & 7)) * 8];
            frag_ab kf1 = *(const frag_ab*)&Ks[cur][(kb * 16 + c16) * 64 + ((4 + quad) ^ (c16 & 7)) * 8];
            s[kb] = __builtin_amdgcn_mfma_f32_16x16x32_bf16(qf[0], kf0, s[kb], 0, 0, 0);
            s[kb] = __builtin_amdgcn_mfma_f32_16x16x32_bf16(qf[1], kf1, s[kb], 0, 0, 0);
        }

        if (t == 0) {
#pragma unroll
            for (int reg = 0; reg < 4; reg++) {
                const int i = qw0 + quad * 4 + reg;
#pragma unroll
                for (int kb = 0; kb < 4; kb++)
                    if (q0 + kb * 16 + c16 > i) s[kb][reg] = -1e30f;
            }
        } else if (t == 4) {
#pragma unroll
            for (int reg = 0; reg < 4; reg++) {
                const int i = qw0 + quad * 4 + reg;
#pragma unroll
                for (int kb = 0; kb < 4; kb++)
                    if (j0 + kb * 16 + c16 + WIN <= i) s[kb][reg] = -1e30f;
            }
        }

        float mt_[4];
#pragma unroll
        for (int reg = 0; reg < 4; reg++)
            mt_[reg] = fmaxf(fmaxf(s[0][reg], s[1][reg]), fmaxf(s[2][reg], s[3][reg]));
#pragma unroll
        for (int off = 1; off < 16; off <<= 1)
#pragma unroll
            for (int reg = 0; reg < 4; reg++) mt_[reg] = fmaxf(mt_[reg], __shfl_xor(mt_[reg], off));

        float alpha[4];
        if (t == 0) {
#pragma unroll
            for (int reg = 0; reg < 4; reg++) m_r[reg] = mt_[reg];
        } else {
#pragma unroll
            for (int reg = 0; reg < 4; reg++) {
                float mn = fmaxf(m_r[reg], mt_[reg]);
                alpha[reg] = __builtin_amdgcn_exp2f(m_r[reg] - mn);
                m_r[reg] = mn;
            }
        }

        float rs[4] = {0.f, 0.f, 0.f, 0.f};
#pragma unroll
        for (int kb = 0; kb < 4; kb++)
#pragma unroll
            for (int reg = 0; reg < 4; reg++) {
                float p = __builtin_amdgcn_exp2f(s[kb][reg] - m_r[reg]);
                union { float f; u32 u; } pu; pu.f = p;
                ps[wave][(quad * 4 + reg) * 72 + kb * 16 + c16] = (u16)(pu.u >> 16);  // RTZ
                rs[reg] += p;
            }
#pragma unroll
        for (int off = 1; off < 16; off <<= 1)
#pragma unroll
            for (int reg = 0; reg < 4; reg++) rs[reg] += __shfl_xor(rs[reg], off);

        if (t == 0) {
#pragma unroll
            for (int reg = 0; reg < 4; reg++) l_r[reg] = rs[reg];
        } else {
#pragma unroll
            for (int reg = 0; reg < 4; reg++) l_r[reg] = l_r[reg] * alpha[reg] + rs[reg];
#pragma unroll
            for (int dblk = 0; dblk < 4; dblk++)
#pragma unroll
                for (int reg = 0; reg < 4; reg++) acc[dblk][reg] *= alpha[reg];
        }

#pragma unroll
        for (int js = 0; js < 2; js++) {
            frag_ab pf = *(const frag_ab*)&ps[wave][c16 * 72 + js * 32 + quad * 8];
#pragma unroll
            for (int dblk = 0; dblk < 4; dblk++) {
                frag_ab vf = *(const frag_ab*)&Vt[(dblk * 16 + c16) * 72 + js * 32 + quad * 8];
                acc[dblk] = __builtin_amdgcn_mfma_f32_16x16x32_bf16(pf, vf, acc[dblk], 0, 0, 0);
            }
        }

        if (pre) {
            __syncthreads();             // all waves done with PV(t) -> Vt overwrite safe
#pragma unroll
            for (int dd = 0; dd < 8; dd++)
                *(u32*)&Vt[(vd8 * 8 + dd) * 72 + vj2] = (u32)va[dd] | ((u32)vb[dd] << 16);
        }
    }

    float inv[4];
#pragma unroll
    for (int reg = 0; reg < 4; reg++) inv[reg] = 1.f / l_r[reg];
#pragma unroll
    for (int dblk = 0; dblk < 4; dblk++)
#pragma unroll
        for (int reg = 0; reg < 4; reg++)
            out[(size_t)(b * SEQ + qw0 + quad * 4 + reg) * 1024 + h * 64 + dblk * 16 + c16] =
                f2bf(acc[dblk][reg] * inv[reg]);
}

extern "C" void kernel_launch(void* const* d_in, const int* in_sizes, int n_in,
                              void* d_out, int out_size, void* d_ws, size_t ws_size,
                              hipStream_t stream) {
    const float* x     = (const float*)d_in[0];   // [2,2048,1024]
    const float* W_qkv = (const float*)d_in[1];   // [1024,3072]
    const float* W_out = (const float*)d_in[2];   // [1024,1024]
    float* out = (float*)d_out;                   // [2,2048,1024]

    char* ws = (char*)d_ws;
    u16* xb    = (u16*)(ws);                       //  8 MB : x bf16 [4096,1024]
    u16* wqkvT = (u16*)(ws + 8388608);             //  6 MB : W_qkv^T bf16 [3072,1024] (q rows pre-scaled)
    u16* woutT = (u16*)(ws + 14680064);            //  2 MB : W_out^T bf16 [1024,1024]
    u16* qkvb  = (u16*)(ws + 16777216);            // 24 MB : qkv bf16 [4096,3072]
    u16* attnb = (u16*)(ws + 41943040);            //  8 MB : attn out bf16 [4096,1024]

    const float QSCALE = 0.125f * 1.4426950408889634f;  // 1/sqrt(64) * log2(e)

    prep_kernel<<<8192, 256, 0, stream>>>(x, W_qkv, W_out, xb, wqkvT, woutT, QSCALE);
    gemm_bk64<true, 128><<<dim3(3 * D_MODEL / 128, NROWS / 128), 256, 0, stream>>>(
        xb, wqkvT, qkvb, NROWS, 3 * D_MODEL, D_MODEL);
    attn_kernel<<<BATCH * N_HEADS * (SEQ / 64), 256, 0, stream>>>(qkvb, attnb);
    gemm_bk64<false, 64><<<dim3(D_MODEL / 128, NROWS / 64), 256, 0, stream>>>(
        attnb, woutT, out, NROWS, D_MODEL, D_MODEL);
}

// Round 7
// 154.351 us; speedup vs baseline: 3.7004x; 1.0013x over previous
//
#include <hip/hip_runtime.h>

typedef unsigned short u16;
typedef unsigned int u32;

#define D_MODEL 1024
#define N_HEADS 16
#define D_HEAD 64
#define WIN 256
#define SEQ 2048
#define BATCH 2
#define NROWS (BATCH*SEQ)          // 4096 token rows

typedef short frag_ab __attribute__((ext_vector_type(8)));   // 8 bf16 (4 VGPRs)
typedef float frag_cd __attribute__((ext_vector_type(4)));   // 4 fp32 (16x16 C/D)
typedef float f32x16 __attribute__((ext_vector_type(16)));   // 32x32 C/D
typedef u16 u16x8 __attribute__((ext_vector_type(8)));

__device__ __forceinline__ u16 f2bf(float f) {
    union { float f; u32 u; } x; x.f = f;
    u32 r = x.u + 0x7fffu + ((x.u >> 16) & 1u);   // RNE
    return (u16)(r >> 16);
}
__device__ __forceinline__ float bf2f(u16 v) {
    union { u32 u; float f; } x; x.u = ((u32)v) << 16; return x.f;
}

__device__ __forceinline__ void load_lds16(const void* g, void* l) {
    __builtin_amdgcn_global_load_lds(
        (const __attribute__((address_space(1))) void*)g,
        (__attribute__((address_space(3))) void*)l, 16, 0, 0);
}

// ---------------- transpose-cast tile helper (caller supplies LDS) ----------------
__device__ __forceinline__ void transpose_tile(const float* __restrict__ W, u16* __restrict__ WT,
                                               int K, int N, int n0, int k0,
                                               int scale_rows, float scale, float (*tile)[33]) {
    int x = threadIdx.x & 31, y = threadIdx.x >> 5;   // 32 x 8
#pragma unroll
    for (int r = 0; r < 4; r++)
        tile[y + 8 * r][x] = W[(size_t)(k0 + y + 8 * r) * N + n0 + x];
    __syncthreads();
#pragma unroll
    for (int r = 0; r < 4; r++) {
        int nrow = n0 + y + 8 * r;
        float v = tile[x][y + 8 * r];
        if (nrow < scale_rows) v *= scale;
        WT[(size_t)nrow * K + k0 + x] = f2bf(v);
    }
}

// ---------------- prep: cast x + transpose-cast W_qkv ----------------
__global__ __launch_bounds__(256) void prep_kernel(const float* __restrict__ x,
                                                   const float* __restrict__ W_qkv,
                                                   u16* __restrict__ xb,
                                                   u16* __restrict__ wqkvT,
                                                   float qscale) {
    __shared__ float tile[32][33];
    const int bid = blockIdx.x;
    if (bid < 4096) {
        int idx = bid * 256 + threadIdx.x;
        float4 v = ((const float4*)x)[idx];
        ushort4 o;
        o.x = f2bf(v.x); o.y = f2bf(v.y); o.z = f2bf(v.z); o.w = f2bf(v.w);
        ((ushort4*)xb)[idx] = o;
    } else {
        int t = bid - 4096;                       // N=3072: 96 x 32 tiles
        transpose_tile(W_qkv, wqkvT, D_MODEL, 3 * D_MODEL, (t % 96) * 32, (t / 96) * 32,
                       D_MODEL, qscale, tile);
    }
}

// ---------------- gemm1 (pipelined): C[M,N] bf16 = A[M,K] * BT[N,K]^T ----------------
// BM=BN=128, BK=64, 256 thr, 32x32x16 frags. Staging: global -> VGPR -> ds_write;
// loads for iter k+1 issued right after the consume barrier of iter k (in flight
// across the whole MFMA block). Barriers bracket only ds_writes (no vmcnt drain).
// XOR-chunk swizzle: chunk of row r at LDS pos (tid&7) holds source chunk (tid&7)^(r&7).
// Grid transposed: blockIdx.x = m-block, blockIdx.y = n-block (consecutive blocks
// share the B-tile -> per-XCD L2 reuse).
__global__ __launch_bounds__(256, 3) void gemm_pipe(const u16* __restrict__ A,
                                                    const u16* __restrict__ BT,
                                                    u16* __restrict__ C,
                                                    int M, int N, int K) {
    __shared__ union SMem {
        struct { u16 As[128 * 64]; u16 Bs[128 * 64]; } s;
        u16 cs[128 * 136];                        // epilogue transpose tile
    } sm;
    const int tid = threadIdx.x;
    const int m0 = blockIdx.x * 128, n0 = blockIdx.y * 128;
    const int wave = tid >> 6, lane = tid & 63;
    const int wm = (wave >> 1) * 64, wn = (wave & 1) * 64;
    const int l32 = lane & 31, kh = lane >> 5;

    f32x16 acc[2][2] = {};

    const int r0 = tid >> 3;                   // 0..31
    const int w  = (tid & 7) ^ (r0 & 7);       // swizzled source chunk
    const u16* aP = A  + (size_t)(m0 + r0) * K + w * 8;
    const u16* bP = BT + (size_t)(n0 + r0) * K + w * 8;

    u16x8 ar[4], br[4];
#pragma unroll
    for (int u = 0; u < 4; u++) {
        ar[u] = *(const u16x8*)(aP + (size_t)(32 * u) * K);
        br[u] = *(const u16x8*)(bP + (size_t)(32 * u) * K);
    }

    for (int k0 = 0; k0 < K; k0 += 64) {
        __syncthreads();                       // consumers done with previous LDS tile
#pragma unroll
        for (int u = 0; u < 4; u++) {
            *(u16x8*)&sm.s.As[(tid + 256 * u) * 8] = ar[u];
            *(u16x8*)&sm.s.Bs[(tid + 256 * u) * 8] = br[u];
        }
        __syncthreads();                       // tile visible (lgkm only)

        if (k0 + 64 < K) {                     // prefetch next iter -> regs (in flight)
#pragma unroll
            for (int u = 0; u < 4; u++) {
                ar[u] = *(const u16x8*)(aP + (size_t)(32 * u) * K + k0 + 64);
                br[u] = *(const u16x8*)(bP + (size_t)(32 * u) * K + k0 + 64);
            }
        }

#pragma unroll
        for (int kk = 0; kk < 4; kk++) {
            const int csel = ((kk * 2 + kh) ^ (l32 & 7)) * 8;
            frag_ab af[2], bf[2];
#pragma unroll
            for (int t = 0; t < 2; t++) {
                af[t] = *(const frag_ab*)&sm.s.As[(wm + t * 32 + l32) * 64 + csel];
                bf[t] = *(const frag_ab*)&sm.s.Bs[(wn + t * 32 + l32) * 64 + csel];
            }
#pragma unroll
            for (int mt = 0; mt < 2; mt++)
#pragma unroll
                for (int nt = 0; nt < 2; nt++)
                    acc[mt][nt] = __builtin_amdgcn_mfma_f32_32x32x16_bf16(af[mt], bf[nt], acc[mt][nt], 0, 0, 0);
        }
    }

    // epilogue: C/D (col=l32, row=(reg&3)+8*(reg>>2)+4*kh [m74/m101]) -> LDS -> coalesced stores
    __syncthreads();
#pragma unroll
    for (int mt = 0; mt < 2; mt++)
#pragma unroll
        for (int nt = 0; nt < 2; nt++) {
            int col = wn + nt * 32 + l32;
#pragma unroll
            for (int reg = 0; reg < 16; reg++) {
                int row = wm + mt * 32 + (reg & 3) + 8 * (reg >> 2) + 4 * kh;
                sm.cs[row * 136 + col] = f2bf(acc[mt][nt][reg]);
            }
        }
    __syncthreads();
    const int cc = tid & 15, rb = tid >> 4;
#pragma unroll
    for (int i = 0; i < 8; i++) {
        int row = rb + 16 * i;
        u16x8 vv = *(const u16x8*)&sm.cs[row * 136 + cc * 8];
        *(u16x8*)(C + (size_t)(m0 + row) * N + n0 + cc * 8) = vv;
    }
}

// ---------------- gemm2: C[M,N] f32 = A[M,K] * BT[N,K]^T, BK=64, 32x32x16, BM=64 ----------------
// (round-6 proven path, grid transposed: blockIdx.x = m-block, y = n-block)
template <int BM>
__global__ __launch_bounds__(256, 4) void gemm_bk64(const u16* __restrict__ A,
                                                    const u16* __restrict__ BT,
                                                    float* __restrict__ C,
                                                    int M, int N, int K) {
    constexpr int MT = BM / 64;
    __shared__ struct { u16 As[BM * 64]; u16 Bs[128 * 64]; } sm;
    const int tid = threadIdx.x;
    const int m0 = blockIdx.x * BM, n0 = blockIdx.y * 128;
    const int wave = tid >> 6, lane = tid & 63;
    const int wm = (wave >> 1) * (BM / 2), wn = (wave & 1) * 64;
    const int l32 = lane & 31, kh = lane >> 5;

    f32x16 acc[MT][2] = {};

    const int r0 = tid >> 3;
    const int w  = (tid & 7) ^ (r0 & 7);
    const u16* aP = A  + (size_t)(m0 + r0) * K + w * 8;
    const u16* bP = BT + (size_t)(n0 + r0) * K + w * 8;

    for (int k0 = 0; k0 < K; k0 += 64) {
        __syncthreads();
#pragma unroll
        for (int u = 0; u < BM / 32; u++)
            load_lds16(aP + (size_t)(32 * u) * K + k0, &sm.As[(tid + 256 * u) * 8]);
#pragma unroll
        for (int u = 0; u < 4; u++)
            load_lds16(bP + (size_t)(32 * u) * K + k0, &sm.Bs[(tid + 256 * u) * 8]);
        __syncthreads();

#pragma unroll
        for (int kk = 0; kk < 4; kk++) {
            const int csel = ((kk * 2 + kh) ^ (l32 & 7)) * 8;
            frag_ab af[MT], bf[2];
#pragma unroll
            for (int t = 0; t < MT; t++)
                af[t] = *(const frag_ab*)&sm.As[(wm + t * 32 + l32) * 64 + csel];
#pragma unroll
            for (int t = 0; t < 2; t++)
                bf[t] = *(const frag_ab*)&sm.Bs[(wn + t * 32 + l32) * 64 + csel];
#pragma unroll
            for (int mt = 0; mt < MT; mt++)
#pragma unroll
                for (int nt = 0; nt < 2; nt++)
                    acc[mt][nt] = __builtin_amdgcn_mfma_f32_32x32x16_bf16(af[mt], bf[nt], acc[mt][nt], 0, 0, 0);
        }
    }

#pragma unroll
    for (int mt = 0; mt < MT; mt++)
#pragma unroll
        for (int nt = 0; nt < 2; nt++) {
            int col = n0 + wn + nt * 32 + l32;
#pragma unroll
            for (int reg = 0; reg < 16; reg++) {
                int row = m0 + wm + mt * 32 + (reg & 3) + 8 * (reg >> 2) + 4 * kh;
                C[(size_t)row * N + col] = acc[mt][nt][reg];
            }
        }
}

// ---------------- MFMA flash attention (sliding window), pipelined ----------------
// Blocks [0,1024): attention. Blocks [1024,2048): W_out transpose-cast (reuses Ks LDS;
// woutT is only consumed by gemm2, which launches after this kernel).
__global__ __launch_bounds__(256) void attn_kernel(const u16* __restrict__ qkv, u16* __restrict__ out,
                                                   const float* __restrict__ W_out,
                                                   u16* __restrict__ woutT) {
    __shared__ u16 Ks[2][64 * 64];       // XOR-chunk-swizzled: chunk c of row r at c^(r&7)
    __shared__ u16 Vt[64 * 72];          // Vt[d][j], row pad +8 (single buffer)
    __shared__ u16 ps[4][16 * 72];       // per-wave P tile, row pad +8

    if (blockIdx.x >= 1024) {            // W_out transpose blocks
        int t = blockIdx.x - 1024;       // 1024 tiles of 32x32
        transpose_tile(W_out, woutT, D_MODEL, D_MODEL, (t & 31) * 32, (t >> 5) * 32,
                       0, 1.0f, (float(*)[33])&Ks[0][0]);
        return;
    }

    const int tid = threadIdx.x;
    const int wave = tid >> 6, lane = tid & 63;
    const int quad = lane >> 4, c16 = lane & 15;

    const int qc = blockIdx.x & 31;
    const int h  = (blockIdx.x >> 5) & 15;
    const int b  = blockIdx.x >> 9;
    const int q0 = qc * 64;
    const int qw0 = q0 + wave * 16;

    frag_ab qf[2];
    {
        const u16* qrow = qkv + (size_t)(b * SEQ + qw0 + c16) * 3072 + h * 64;
        qf[0] = *(const frag_ab*)(qrow + quad * 8);
        qf[1] = *(const frag_ab*)(qrow + 32 + quad * 8);
    }

    float m_r[4], l_r[4];
    frag_cd acc[4] = {};

    const int ntiles = qc < 4 ? qc + 1 : 5;

    const int krow = wave * 16 + (lane >> 3);
    const int kchunk = (lane & 7) ^ (lane >> 3);
    const int vj2 = (tid & 31) * 2, vd8 = tid >> 5;

    const u16* kbase = qkv + (size_t)(b * SEQ + krow) * 3072 + 1024 + h * 64 + kchunk * 8;
    const u16* vbase = qkv + (size_t)(b * SEQ + vj2) * 3072 + 2048 + h * 64 + vd8 * 8;

    u16x8 va, vb;
    {
        const u16* g = kbase + (size_t)q0 * 3072;
        load_lds16(g,            &Ks[0][krow * 64 + (lane & 7) * 8]);
        load_lds16(g + 8 * 3072, &Ks[0][(krow + 8) * 64 + (lane & 7) * 8]);
        const u16* gv = vbase + (size_t)q0 * 3072;
        va = *(const u16x8*)gv;
        vb = *(const u16x8*)(gv + 3072);
#pragma unroll
        for (int dd = 0; dd < 8; dd++)
            *(u32*)&Vt[(vd8 * 8 + dd) * 72 + vj2] = (u32)va[dd] | ((u32)vb[dd] << 16);
    }

    for (int t = 0; t < ntiles; t++) {
        const int cur = t & 1, nxt = cur ^ 1;
        const int j0 = q0 - 64 * t;
        __syncthreads();                 // Ks[cur] + Vt staged & visible
        const bool pre = (t + 1 < ntiles);
        if (pre) {                       // prefetch t+1: K -> LDS[nxt] (async), V -> regs
            const u16* g = kbase + (size_t)(j0 - 64) * 3072;
            load_lds16(g,            &Ks[nxt][krow * 64 + (lane & 7) * 8]);
            load_lds16(g + 8 * 3072, &Ks[nxt][(krow + 8) * 64 + (lane & 7) * 8]);
            const u16* gv = vbase + (size_t)(j0 - 64) * 3072;
            va = *(const u16x8*)gv;
            vb = *(const u16x8*)(gv + 3072);
        }

        frag_cd s[4] = {};
#pragma unroll
        for (int kb = 0; kb < 4; kb++) {
            frag_ab kf0 = *(const frag_ab*)&Ks[cur][(kb * 16 + c16) * 64 + ((quad    ) ^ (c16 & 7)) * 8];
            frag_ab kf1 = *(const frag_ab*)&Ks[cur][(kb * 16 + c16) * 64 + ((4 + quad) ^ (c16 & 7)) * 8];
            s[kb] = __builtin_amdgcn_mfma_f32_16x16x32_bf16(qf[0], kf0, s[kb], 0, 0, 0);
            s[kb] = __builtin_amdgcn_mfma_f32_16x16x32_bf16(qf[1], kf1, s[kb], 0, 0, 0);
        }

        if (t == 0) {
#pragma unroll
            for (int reg = 0; reg < 4; reg++) {
                const int i = qw0 + quad * 4 + reg;
#pragma unroll
                for (int kb = 0; kb < 4; kb++)
                    if (q0 + kb * 16 + c16 > i) s[kb][reg] = -1e30f;
            }
        } else if (t == 4) {
#pragma unroll
            for (int reg = 0; reg < 4; reg++) {
                const int i = qw0 + quad * 4 + reg;
#pragma unroll
                for (int kb = 0; kb < 4; kb++)
                    if (j0 + kb * 16 + c16 + WIN <= i) s[kb][reg] = -1e30f;
            }
        }

        float mt_[4];
#pragma unroll
        for (int reg = 0; reg < 4; reg++)
            mt_[reg] = fmaxf(fmaxf(s[0][reg], s[1][reg]), fmaxf(s[2][reg], s[3][reg]));
#pragma unroll
        for (int off = 1; off < 16; off <<= 1)
#pragma unroll
            for (int reg = 0; reg < 4; reg++) mt_[reg] = fmaxf(mt_[reg], __shfl_xor(mt_[reg], off));

        float alpha[4];
        if (t == 0) {
#pragma unroll
            for (int reg = 0; reg < 4; reg++) m_r[reg] = mt_[reg];
        } else {
#pragma unroll
            for (int reg = 0; reg < 4; reg++) {
                float mn = fmaxf(m_r[reg], mt_[reg]);
                alpha[reg] = __builtin_amdgcn_exp2f(m_r[reg] - mn);
                m_r[reg] = mn;
            }
        }

        float rs[4] = {0.f, 0.f, 0.f, 0.f};
#pragma unroll
        for (int kb = 0; kb < 4; kb++)
#pragma unroll
            for (int reg = 0; reg < 4; reg++) {
                float p = __builtin_amdgcn_exp2f(s[kb][reg] - m_r[reg]);
                union { float f; u32 u; } pu; pu.f = p;
                ps[wave][(quad * 4 + reg) * 72 + kb * 16 + c16] = (u16)(pu.u >> 16);  // RTZ
                rs[reg] += p;
            }
#pragma unroll
        for (int off = 1; off < 16; off <<= 1)
#pragma unroll
            for (int reg = 0; reg < 4; reg++) rs[reg] += __shfl_xor(rs[reg], off);

        if (t == 0) {
#pragma unroll
            for (int reg = 0; reg < 4; reg++) l_r[reg] = rs[reg];
        } else {
#pragma unroll
            for (int reg = 0; reg < 4; reg++) l_r[reg] = l_r[reg] * alpha[reg] + rs[reg];
#pragma unroll
            for (int dblk = 0; dblk < 4; dblk++)
#pragma unroll
                for (int reg = 0; reg < 4; reg++) acc[dblk][reg] *= alpha[reg];
        }

#pragma unroll
        for (int js = 0; js < 2; js++) {
            frag_ab pf = *(const frag_ab*)&ps[wave][c16 * 72 + js * 32 + quad * 8];
#pragma unroll
            for (int dblk = 0; dblk < 4; dblk++) {
                frag_ab vf = *(const frag_ab*)&Vt[(dblk * 16 + c16) * 72 + js * 32 + quad * 8];
                acc[dblk] = __builtin_amdgcn_mfma_f32_16x16x32_bf16(pf, vf, acc[dblk], 0, 0, 0);
            }
        }

        if (pre) {
            __syncthreads();             // all waves done with PV(t) -> Vt overwrite safe
#pragma unroll
            for (int dd = 0; dd < 8; dd++)
                *(u32*)&Vt[(vd8 * 8 + dd) * 72 + vj2] = (u32)va[dd] | ((u32)vb[dd] << 16);
        }
    }

    float inv[4];
#pragma unroll
    for (int reg = 0; reg < 4; reg++) inv[reg] = 1.f / l_r[reg];
#pragma unroll
    for (int dblk = 0; dblk < 4; dblk++)
#pragma unroll
        for (int reg = 0; reg < 4; reg++)
            out[(size_t)(b * SEQ + qw0 + quad * 4 + reg) * 1024 + h * 64 + dblk * 16 + c16] =
                f2bf(acc[dblk][reg] * inv[reg]);
}

extern "C" void kernel_launch(void* const* d_in, const int* in_sizes, int n_in,
                              void* d_out, int out_size, void* d_ws, size_t ws_size,
                              hipStream_t stream) {
    const float* x     = (const float*)d_in[0];   // [2,2048,1024]
    const float* W_qkv = (const float*)d_in[1];   // [1024,3072]
    const float* W_out = (const float*)d_in[2];   // [1024,1024]
    float* out = (float*)d_out;                   // [2,2048,1024]

    char* ws = (char*)d_ws;
    u16* xb    = (u16*)(ws);                       //  8 MB : x bf16 [4096,1024]
    u16* wqkvT = (u16*)(ws + 8388608);             //  6 MB : W_qkv^T bf16 [3072,1024] (q rows pre-scaled)
    u16* woutT = (u16*)(ws + 14680064);            //  2 MB : W_out^T bf16 [1024,1024]
    u16* qkvb  = (u16*)(ws + 16777216);            // 24 MB : qkv bf16 [4096,3072]
    u16* attnb = (u16*)(ws + 41943040);            //  8 MB : attn out bf16 [4096,1024]

    const float QSCALE = 0.125f * 1.4426950408889634f;  // 1/sqrt(64) * log2(e)

    prep_kernel<<<7168, 256, 0, stream>>>(x, W_qkv, xb, wqkvT, QSCALE);
    // gemm1: grid transposed (x = m-block, y = n-block -> consecutive blocks share B-tile)
    gemm_pipe<<<dim3(NROWS / 128, 3 * D_MODEL / 128), 256, 0, stream>>>(
        xb, wqkvT, qkvb, NROWS, 3 * D_MODEL, D_MODEL);
    // attn (1024 blocks) + W_out transpose (1024 blocks)
    attn_kernel<<<2048, 256, 0, stream>>>(qkvb, attnb, W_out, woutT);
    // gemm2: grid transposed
    gemm_bk64<64><<<dim3(NROWS / 64, D_MODEL / 128), 256, 0, stream>>>(
        attnb, woutT, out, NROWS, D_MODEL, D_MODEL);
}